// Round 1
// baseline (2814.312 us; speedup 1.0000x reference)
//
#include <hip/hip_runtime.h>
#include <cmath>

#define NN 100000
#define EE 1600000
#define INC 500
#define HIDC 128
#define OUTC 64
#define NLAYER 8

// ---------------- graph preprocessing ----------------

__global__ void k_count_deg(const int* __restrict__ dst, int* __restrict__ deg, int E) {
  int e = blockIdx.x * blockDim.x + threadIdx.x;
  if (e < E) atomicAdd(&deg[dst[e]], 1);
}

__global__ void k_scan_block_sums(const int* __restrict__ deg, int* __restrict__ bsum, int n) {
  __shared__ int sm[256];
  int i = blockIdx.x * 256 + threadIdx.x;
  int v = (i < n) ? deg[i] + 1 : 0;  // +1 for self-loop
  sm[threadIdx.x] = v;
  __syncthreads();
  for (int s = 128; s > 0; s >>= 1) {
    if (threadIdx.x < s) sm[threadIdx.x] += sm[threadIdx.x + s];
    __syncthreads();
  }
  if (threadIdx.x == 0) bsum[blockIdx.x] = sm[0];
}

__global__ void k_scan_partials(int* __restrict__ bsum, int nb) {
  __shared__ int sm[512];
  int t = threadIdx.x;
  sm[t] = (t < nb) ? bsum[t] : 0;
  __syncthreads();
  for (int s = 1; s < 512; s <<= 1) {
    int v = (t >= s) ? sm[t - s] : 0;
    __syncthreads();
    sm[t] += v;
    __syncthreads();
  }
  if (t < nb) bsum[t] = (t == 0) ? 0 : sm[t - 1];  // exclusive
}

__global__ void k_scan_final(const int* __restrict__ deg, const int* __restrict__ bsum,
                             int* __restrict__ row_ptr, int n) {
  __shared__ int sm[256];
  int i = blockIdx.x * 256 + threadIdx.x;
  int v = (i < n) ? deg[i] + 1 : 0;
  sm[threadIdx.x] = v;
  __syncthreads();
  for (int s = 1; s < 256; s <<= 1) {
    int u = (threadIdx.x >= s) ? sm[threadIdx.x - s] : 0;
    __syncthreads();
    sm[threadIdx.x] += u;
    __syncthreads();
  }
  if (i < n) row_ptr[i] = bsum[blockIdx.x] + sm[threadIdx.x] - v;  // exclusive
}

__global__ void k_init_rows(const int* __restrict__ deg, const int* __restrict__ row_ptr,
                            int* __restrict__ cursor, int* __restrict__ col,
                            float* __restrict__ dinv, int n) {
  int i = blockIdx.x * blockDim.x + threadIdx.x;
  if (i < n) {
    int rp = row_ptr[i];
    col[rp] = i;          // self-loop entry first (deterministic)
    cursor[i] = rp + 1;
    dinv[i] = rsqrtf((float)(deg[i] + 1));
  }
}

__global__ void k_fill_edges(const int* __restrict__ src, const int* __restrict__ dst,
                             int* __restrict__ cursor, int* __restrict__ col, int E) {
  int e = blockIdx.x * blockDim.x + threadIdx.x;
  if (e < E) {
    int pos = atomicAdd(&cursor[dst[e]], 1);
    col[pos] = src[e];
  }
}

// ---------------- aggregation: z = (1-a)*Ahat*h + a*h0 ----------------
// one wave per destination node; lane holds features (2*lane, 2*lane+1)

__global__ void __launch_bounds__(256) k_agg(
    const float* __restrict__ h, const float* __restrict__ h0, float* __restrict__ z,
    const int* __restrict__ row_ptr, const int* __restrict__ deg,
    const int* __restrict__ col, const float* __restrict__ dinv) {
  int wid = (blockIdx.x * blockDim.x + threadIdx.x) >> 6;
  int lane = threadIdx.x & 63;
  if (wid >= NN) return;
  int start = row_ptr[wid];
  int cnt = deg[wid] + 1;
  const float2* __restrict__ h2 = (const float2*)h;
  float ax = 0.f, ay = 0.f;
  int c = col[start];
  for (int i = 0; i < cnt; ++i) {
    int cn = (i + 1 < cnt) ? col[start + i + 1] : 0;  // prefetch next index
    float dc = dinv[c];
    float2 v = h2[(size_t)c * 64 + lane];
    ax = fmaf(dc, v.x, ax);
    ay = fmaf(dc, v.y, ay);
    c = cn;
  }
  float dr = dinv[wid] * 0.9f;  // (1-ALPHA) * dinv[dst]
  float2 r0 = ((const float2*)h0)[(size_t)wid * 64 + lane];
  float2 zo;
  zo.x = fmaf(dr, ax, 0.1f * r0.x);
  zo.y = fmaf(dr, ay, 0.1f * r0.y);
  ((float2*)z)[(size_t)wid * 64 + lane] = zo;
}

// ---------------- tiled fp32 GEMM with fused epilogues ----------------
// EPI 0: C = relu(A@B + bias)             (input projection)
// EPI 1: C = relu(p0*A + p1*(A@B))        (GCNII layer; needs BN == K)
// EPI 2: C = A@B + bias                   (output projection)

template <int BN, int EPI>
__global__ void __launch_bounds__(256) k_gemm(
    const float* __restrict__ A, const float* __restrict__ B,
    const float* __restrict__ bias, float* __restrict__ C,
    int M, int K, float p0, float p1) {
  constexpr int BM = 64, BK = 32, TM = 4, TN = BN / 16;
  __shared__ float As[BM * (BK + 1)];
  __shared__ float Bs[BK * BN];
  int tid = threadIdx.x;
  int tx = tid & 15, ty = tid >> 4;
  int row0 = blockIdx.x * BM;

  float acc[TM][TN];
#pragma unroll
  for (int i = 0; i < TM; ++i)
#pragma unroll
    for (int j = 0; j < TN; ++j) acc[i][j] = 0.f;

  for (int kt = 0; kt < K; kt += BK) {
    for (int i = tid; i < BM * BK; i += 256) {
      int r = i / BK, cc = i % BK;
      int gr = row0 + r, gk = kt + cc;
      As[r * (BK + 1) + cc] = (gr < M && gk < K) ? A[(size_t)gr * K + gk] : 0.f;
    }
    for (int i = tid; i < BK * BN; i += 256) {
      int r = i / BN, cc = i % BN;
      int gk = kt + r;
      Bs[i] = (gk < K) ? B[(size_t)gk * BN + cc] : 0.f;
    }
    __syncthreads();
#pragma unroll
    for (int k = 0; k < BK; ++k) {
      float a[TM];
#pragma unroll
      for (int ri = 0; ri < TM; ++ri) a[ri] = As[(ty * TM + ri) * (BK + 1) + k];
      float b[TN];
      const float4* b4 = reinterpret_cast<const float4*>(&Bs[k * BN + tx * TN]);
#pragma unroll
      for (int j = 0; j < TN / 4; ++j) {
        float4 t = b4[j];
        b[j * 4 + 0] = t.x; b[j * 4 + 1] = t.y; b[j * 4 + 2] = t.z; b[j * 4 + 3] = t.w;
      }
#pragma unroll
      for (int ri = 0; ri < TM; ++ri)
#pragma unroll
        for (int ci = 0; ci < TN; ++ci)
          acc[ri][ci] = fmaf(a[ri], b[ci], acc[ri][ci]);
    }
    __syncthreads();
  }

#pragma unroll
  for (int ri = 0; ri < TM; ++ri) {
    int gr = row0 + ty * TM + ri;
    if (gr >= M) continue;
#pragma unroll
    for (int j = 0; j < TN / 4; ++j) {
      float4 o;
      float* op = &o.x;
#pragma unroll
      for (int q = 0; q < 4; ++q) {
        int ccol = tx * TN + j * 4 + q;
        float v = acc[ri][j * 4 + q];
        if (EPI == 0) { v += bias[ccol]; v = v > 0.f ? v : 0.f; }
        else if (EPI == 1) { float zv = A[(size_t)gr * K + ccol]; v = fmaf(p0, zv, p1 * v); v = v > 0.f ? v : 0.f; }
        else { v += bias[ccol]; }
        op[q] = v;
      }
      reinterpret_cast<float4*>(&C[(size_t)gr * BN + tx * TN + j * 4])[0] = o;
    }
  }
}

// ---------------- launch ----------------

extern "C" void kernel_launch(void* const* d_in, const int* in_sizes, int n_in,
                              void* d_out, int out_size, void* d_ws, size_t ws_size,
                              hipStream_t stream) {
  const float* x     = (const float*)d_in[0];
  const int*   ei    = (const int*)d_in[1];
  const float* W_in  = (const float*)d_in[2];
  const float* b_in  = (const float*)d_in[3];
  const float* W_cv  = (const float*)d_in[4];
  const float* W_out = (const float*)d_in[5];
  const float* b_out = (const float*)d_in[6];
  float* out = (float*)d_out;

  char* ws = (char*)d_ws;
  size_t off = 0;
  auto alloc = [&](size_t bytes) {
    char* p = ws + off;
    off = (off + bytes + 255) & ~(size_t)255;
    return p;
  };
  int*   deg     = (int*)alloc((size_t)NN * 4);
  int*   row_ptr = (int*)alloc((size_t)NN * 4);
  int*   cursor  = (int*)alloc((size_t)NN * 4);
  int*   bsum    = (int*)alloc(512 * 4);
  float* dinv    = (float*)alloc((size_t)NN * 4);
  int*   col     = (int*)alloc((size_t)(EE + NN) * 4);
  float* h0      = (float*)alloc((size_t)NN * HIDC * 4);
  float* zb      = (float*)alloc((size_t)NN * HIDC * 4);
  float* hb      = (float*)alloc((size_t)NN * HIDC * 4);

  const int* srcp = ei;
  const int* dstp = ei + EE;

  hipMemsetAsync(deg, 0, (size_t)NN * 4, stream);
  k_count_deg<<<(EE + 255) / 256, 256, 0, stream>>>(dstp, deg, EE);
  int nb = (NN + 255) / 256;  // 391 <= 512
  k_scan_block_sums<<<nb, 256, 0, stream>>>(deg, bsum, NN);
  k_scan_partials<<<1, 512, 0, stream>>>(bsum, nb);
  k_scan_final<<<nb, 256, 0, stream>>>(deg, bsum, row_ptr, NN);
  k_init_rows<<<(NN + 255) / 256, 256, 0, stream>>>(deg, row_ptr, cursor, col, dinv, NN);
  k_fill_edges<<<(EE + 255) / 256, 256, 0, stream>>>(srcp, dstp, cursor, col, EE);

  int gblk = (NN + 63) / 64;
  // h0 = relu(x @ W_in + b_in)
  k_gemm<128, 0><<<gblk, 256, 0, stream>>>(x, W_in, b_in, h0, NN, INC, 0.f, 0.f);

  const float* hcur = h0;
  for (int l = 0; l < NLAYER; ++l) {
    k_agg<<<((size_t)NN * 64 + 255) / 256, 256, 0, stream>>>(hcur, h0, zb, row_ptr, deg, col, dinv);
    float beta = logf(0.5f / (float)(l + 1) + 1.0f);
    // h = relu((1-beta)*z + beta*(z @ W_conv[l]))
    k_gemm<128, 1><<<gblk, 256, 0, stream>>>(zb, W_cv + (size_t)l * HIDC * HIDC, nullptr, hb, NN, HIDC,
                                             1.0f - beta, beta);
    hcur = hb;
  }
  // out = h @ W_out + b_out
  k_gemm<64, 2><<<gblk, 256, 0, stream>>>(hcur, W_out, b_out, out, NN, HIDC, 0.f, 0.f);
}

// Round 2
// 2355.624 us; speedup vs baseline: 1.1947x; 1.1947x over previous
//
#include <hip/hip_runtime.h>
#include <cmath>

#define NN 100000
#define EE 1600000
#define INC 500
#define HIDC 128
#define OUTC 64
#define NLAYER 8

// ---------------- graph preprocessing ----------------

__global__ void k_count_deg(const int* __restrict__ dst, int* __restrict__ deg, int E) {
  int e = blockIdx.x * blockDim.x + threadIdx.x;
  if (e < E) atomicAdd(&deg[dst[e]], 1);
}

__global__ void k_scan_block_sums(const int* __restrict__ deg, int* __restrict__ bsum, int n) {
  __shared__ int sm[256];
  int i = blockIdx.x * 256 + threadIdx.x;
  int v = (i < n) ? deg[i] + 1 : 0;  // +1 for self-loop
  sm[threadIdx.x] = v;
  __syncthreads();
  for (int s = 128; s > 0; s >>= 1) {
    if (threadIdx.x < s) sm[threadIdx.x] += sm[threadIdx.x + s];
    __syncthreads();
  }
  if (threadIdx.x == 0) bsum[blockIdx.x] = sm[0];
}

__global__ void k_scan_partials(int* __restrict__ bsum, int nb) {
  __shared__ int sm[512];
  int t = threadIdx.x;
  sm[t] = (t < nb) ? bsum[t] : 0;
  __syncthreads();
  for (int s = 1; s < 512; s <<= 1) {
    int v = (t >= s) ? sm[t - s] : 0;
    __syncthreads();
    sm[t] += v;
    __syncthreads();
  }
  if (t < nb) bsum[t] = (t == 0) ? 0 : sm[t - 1];  // exclusive
}

__global__ void k_scan_final(const int* __restrict__ deg, const int* __restrict__ bsum,
                             int* __restrict__ row_ptr, int n) {
  __shared__ int sm[256];
  int i = blockIdx.x * 256 + threadIdx.x;
  int v = (i < n) ? deg[i] + 1 : 0;
  sm[threadIdx.x] = v;
  __syncthreads();
  for (int s = 1; s < 256; s <<= 1) {
    int u = (threadIdx.x >= s) ? sm[threadIdx.x - s] : 0;
    __syncthreads();
    sm[threadIdx.x] += u;
    __syncthreads();
  }
  if (i < n) row_ptr[i] = bsum[blockIdx.x] + sm[threadIdx.x] - v;  // exclusive
}

__global__ void k_init_rows(const int* __restrict__ deg, const int* __restrict__ row_ptr,
                            int* __restrict__ cursor, int* __restrict__ col,
                            float* __restrict__ dinv, int n) {
  int i = blockIdx.x * blockDim.x + threadIdx.x;
  if (i < n) {
    int rp = row_ptr[i];
    col[rp] = i;          // self-loop entry first (deterministic)
    cursor[i] = rp + 1;
    dinv[i] = rsqrtf((float)(deg[i] + 1));
  }
}

__global__ void k_fill_edges(const int* __restrict__ src, const int* __restrict__ dst,
                             int* __restrict__ cursor, int* __restrict__ col, int E) {
  int e = blockIdx.x * blockDim.x + threadIdx.x;
  if (e < E) {
    int pos = atomicAdd(&cursor[dst[e]], 1);
    col[pos] = src[e];
  }
}

// ---------------- aggregation: z = (1-a)*Ahat*h + a*h0 ----------------
// one wave per destination node; lane holds features (2*lane, 2*lane+1)

__global__ void __launch_bounds__(256) k_agg(
    const float* __restrict__ h, const float* __restrict__ h0, float* __restrict__ z,
    const int* __restrict__ row_ptr, const int* __restrict__ deg,
    const int* __restrict__ col, const float* __restrict__ dinv) {
  int wid = (blockIdx.x * blockDim.x + threadIdx.x) >> 6;
  int lane = threadIdx.x & 63;
  if (wid >= NN) return;
  int start = row_ptr[wid];
  int cnt = deg[wid] + 1;
  const float2* __restrict__ h2 = (const float2*)h;
  float ax = 0.f, ay = 0.f;
  int c = col[start];
  for (int i = 0; i < cnt; ++i) {
    int cn = (i + 1 < cnt) ? col[start + i + 1] : 0;  // prefetch next index
    float dc = dinv[c];
    float2 v = h2[(size_t)c * 64 + lane];
    ax = fmaf(dc, v.x, ax);
    ay = fmaf(dc, v.y, ay);
    c = cn;
  }
  float dr = dinv[wid] * 0.9f;  // (1-ALPHA) * dinv[dst]
  float2 r0 = ((const float2*)h0)[(size_t)wid * 64 + lane];
  float2 zo;
  zo.x = fmaf(dr, ax, 0.1f * r0.x);
  zo.y = fmaf(dr, ay, 0.1f * r0.y);
  ((float2*)z)[(size_t)wid * 64 + lane] = zo;
}

// ---------------- tiled fp32 GEMM, 128xBN block, 8x(TN) micro-tile ----------------
// EPI 0: C = relu(A@B + bias)             (input projection)
// EPI 1: C = relu(p0*A + p1*(A@B))        (GCNII layer; BN == K == 128)
// EPI 2: C = A@B + bias                   (output projection)

template <int BN, int EPI>
__global__ void __launch_bounds__(256) k_gemm(
    const float* __restrict__ A, const float* __restrict__ B,
    const float* __restrict__ bias, float* __restrict__ C,
    int M, int K, float p0, float p1) {
  constexpr int BM = 128, BK = 32;
  constexpr int TN = (BN == 128) ? 8 : 4;  // per-thread columns (in blocks of 4)
  constexpr int NCB = TN / 4;              // 1 or 2 column blocks
  __shared__ float As[BK][BM + 4];         // transposed A tile; 132 keeps rows 16B-aligned
  __shared__ float Bs[BK][BN];
  int tid = threadIdx.x;
  int tx = tid & 15, ty = tid >> 4;
  int row0 = blockIdx.x * BM;

  float acc[8][TN];
#pragma unroll
  for (int i = 0; i < 8; ++i)
#pragma unroll
    for (int j = 0; j < TN; ++j) acc[i][j] = 0.f;

  for (int kt = 0; kt < K; kt += BK) {
    // stage A (transposed): 128 rows x 32 k, 4 float4 per thread
#pragma unroll
    for (int p = 0; p < 4; ++p) {
      int j = tid + p * 256;
      int r = j >> 3;              // 0..127
      int c4 = (j & 7) << 2;       // 0,4,...,28
      int gr = row0 + r, gk = kt + c4;
      float4 v = make_float4(0.f, 0.f, 0.f, 0.f);
      if (gr < M && gk < K) {
        v = *reinterpret_cast<const float4*>(&A[(size_t)gr * K + gk]);  // K % 4 == 0 always
      }
      As[c4 + 0][r] = v.x;
      As[c4 + 1][r] = v.y;
      As[c4 + 2][r] = v.z;
      As[c4 + 3][r] = v.w;
    }
    // stage B: 32 x BN
    constexpr int BF4 = BK * BN / 4;
#pragma unroll
    for (int p = 0; p < BF4 / 256; ++p) {
      int j = tid + p * 256;
      int r = j / (BN / 4);
      int c4 = (j % (BN / 4)) * 4;
      int gk = kt + r;
      float4 v = make_float4(0.f, 0.f, 0.f, 0.f);
      if (gk < K) v = *reinterpret_cast<const float4*>(&B[(size_t)gk * BN + c4]);
      *reinterpret_cast<float4*>(&Bs[r][c4]) = v;
    }
    __syncthreads();

#pragma unroll 8
    for (int k = 0; k < BK; ++k) {
      float4 a0 = *reinterpret_cast<const float4*>(&As[k][ty * 8]);      // broadcast reads
      float4 a1 = *reinterpret_cast<const float4*>(&As[k][ty * 8 + 4]);
      float a[8] = {a0.x, a0.y, a0.z, a0.w, a1.x, a1.y, a1.z, a1.w};
      float b[TN];
      float4 b0 = *reinterpret_cast<const float4*>(&Bs[k][tx * 4]);      // spans all 32 banks
      b[0] = b0.x; b[1] = b0.y; b[2] = b0.z; b[3] = b0.w;
      if (NCB == 2) {
        float4 b1 = *reinterpret_cast<const float4*>(&Bs[k][64 + tx * 4]);
        b[4] = b1.x; b[5] = b1.y; b[6] = b1.z; b[7] = b1.w;
      }
#pragma unroll
      for (int ri = 0; ri < 8; ++ri)
#pragma unroll
        for (int ci = 0; ci < TN; ++ci)
          acc[ri][ci] = fmaf(a[ri], b[ci], acc[ri][ci]);
    }
    __syncthreads();
  }

#pragma unroll
  for (int ri = 0; ri < 8; ++ri) {
    int gr = row0 + ty * 8 + ri;
    if (gr >= M) continue;
#pragma unroll
    for (int cb = 0; cb < NCB; ++cb) {
      int colb = cb * 64 + tx * 4;
      float4 o;
      float* op = &o.x;
      float4 zv4;
      if (EPI == 1) zv4 = *reinterpret_cast<const float4*>(&A[(size_t)gr * K + colb]);
      const float* zp = &zv4.x;
#pragma unroll
      for (int q = 0; q < 4; ++q) {
        float v = acc[ri][cb * 4 + q];
        if (EPI == 0) { v += bias[colb + q]; v = fmaxf(v, 0.f); }
        else if (EPI == 1) { v = fmaf(p0, zp[q], p1 * v); v = fmaxf(v, 0.f); }
        else { v += bias[colb + q]; }
        op[q] = v;
      }
      *reinterpret_cast<float4*>(&C[(size_t)gr * BN + colb]) = o;
    }
  }
}

// ---------------- launch ----------------

extern "C" void kernel_launch(void* const* d_in, const int* in_sizes, int n_in,
                              void* d_out, int out_size, void* d_ws, size_t ws_size,
                              hipStream_t stream) {
  const float* x     = (const float*)d_in[0];
  const int*   ei    = (const int*)d_in[1];
  const float* W_in  = (const float*)d_in[2];
  const float* b_in  = (const float*)d_in[3];
  const float* W_cv  = (const float*)d_in[4];
  const float* W_out = (const float*)d_in[5];
  const float* b_out = (const float*)d_in[6];
  float* out = (float*)d_out;

  char* ws = (char*)d_ws;
  size_t off = 0;
  auto alloc = [&](size_t bytes) {
    char* p = ws + off;
    off = (off + bytes + 255) & ~(size_t)255;
    return p;
  };
  int*   deg     = (int*)alloc((size_t)NN * 4);
  int*   row_ptr = (int*)alloc((size_t)NN * 4);
  int*   cursor  = (int*)alloc((size_t)NN * 4);
  int*   bsum    = (int*)alloc(512 * 4);
  float* dinv    = (float*)alloc((size_t)NN * 4);
  int*   col     = (int*)alloc((size_t)(EE + NN) * 4);
  float* h0      = (float*)alloc((size_t)NN * HIDC * 4);
  float* zb      = (float*)alloc((size_t)NN * HIDC * 4);
  float* hb      = (float*)alloc((size_t)NN * HIDC * 4);

  const int* srcp = ei;
  const int* dstp = ei + EE;

  hipMemsetAsync(deg, 0, (size_t)NN * 4, stream);
  k_count_deg<<<(EE + 255) / 256, 256, 0, stream>>>(dstp, deg, EE);
  int nb = (NN + 255) / 256;  // 391 <= 512
  k_scan_block_sums<<<nb, 256, 0, stream>>>(deg, bsum, NN);
  k_scan_partials<<<1, 512, 0, stream>>>(bsum, nb);
  k_scan_final<<<nb, 256, 0, stream>>>(deg, bsum, row_ptr, NN);
  k_init_rows<<<(NN + 255) / 256, 256, 0, stream>>>(deg, row_ptr, cursor, col, dinv, NN);
  k_fill_edges<<<(EE + 255) / 256, 256, 0, stream>>>(srcp, dstp, cursor, col, EE);

  int gblk = (NN + 127) / 128;
  // h0 = relu(x @ W_in + b_in)
  k_gemm<128, 0><<<gblk, 256, 0, stream>>>(x, W_in, b_in, h0, NN, INC, 0.f, 0.f);

  const float* hcur = h0;
  for (int l = 0; l < NLAYER; ++l) {
    k_agg<<<((size_t)NN * 64 + 255) / 256, 256, 0, stream>>>(hcur, h0, zb, row_ptr, deg, col, dinv);
    float beta = logf(0.5f / (float)(l + 1) + 1.0f);
    // h = relu((1-beta)*z + beta*(z @ W_conv[l]))
    k_gemm<128, 1><<<gblk, 256, 0, stream>>>(zb, W_cv + (size_t)l * HIDC * HIDC, nullptr, hb, NN, HIDC,
                                             1.0f - beta, beta);
    hcur = hb;
  }
  // out = h @ W_out + b_out
  k_gemm<64, 2><<<gblk, 256, 0, stream>>>(hcur, W_out, b_out, out, NN, HIDC, 0.f, 0.f);
}

// Round 3
// 2249.253 us; speedup vs baseline: 1.2512x; 1.0473x over previous
//
#include <hip/hip_runtime.h>
#include <cmath>

#define NN 100000
#define EE 1600000
#define INC 500
#define HIDC 128
#define OUTC 64
#define NLAYER 8

typedef float f32x4 __attribute__((ext_vector_type(4)));
typedef __bf16 bf16x8 __attribute__((ext_vector_type(8)));
typedef short s16x4 __attribute__((ext_vector_type(4)));
typedef short s16x8 __attribute__((ext_vector_type(8)));

__device__ __forceinline__ unsigned short f2bf_rn(float f) {
  unsigned u = __float_as_uint(f);
  unsigned r = u + 0x7fffu + ((u >> 16) & 1u);
  return (unsigned short)(r >> 16);
}
__device__ __forceinline__ float bf2f(unsigned short h) {
  return __uint_as_float(((unsigned)h) << 16);
}

// ---------------- graph preprocessing ----------------

__global__ void k_count_deg(const int* __restrict__ dst, int* __restrict__ deg, int E) {
  int e = blockIdx.x * blockDim.x + threadIdx.x;
  if (e < E) atomicAdd(&deg[dst[e]], 1);
}

__global__ void k_scan_block_sums(const int* __restrict__ deg, int* __restrict__ bsum, int n) {
  __shared__ int sm[256];
  int i = blockIdx.x * 256 + threadIdx.x;
  int v = (i < n) ? deg[i] + 1 : 0;  // +1 for self-loop
  sm[threadIdx.x] = v;
  __syncthreads();
  for (int s = 128; s > 0; s >>= 1) {
    if (threadIdx.x < s) sm[threadIdx.x] += sm[threadIdx.x + s];
    __syncthreads();
  }
  if (threadIdx.x == 0) bsum[blockIdx.x] = sm[0];
}

__global__ void k_scan_partials(int* __restrict__ bsum, int nb) {
  __shared__ int sm[512];
  int t = threadIdx.x;
  sm[t] = (t < nb) ? bsum[t] : 0;
  __syncthreads();
  for (int s = 1; s < 512; s <<= 1) {
    int v = (t >= s) ? sm[t - s] : 0;
    __syncthreads();
    sm[t] += v;
    __syncthreads();
  }
  if (t < nb) bsum[t] = (t == 0) ? 0 : sm[t - 1];  // exclusive
}

__global__ void k_scan_final(const int* __restrict__ deg, const int* __restrict__ bsum,
                             int* __restrict__ row_ptr, int n) {
  __shared__ int sm[256];
  int i = blockIdx.x * 256 + threadIdx.x;
  int v = (i < n) ? deg[i] + 1 : 0;
  sm[threadIdx.x] = v;
  __syncthreads();
  for (int s = 1; s < 256; s <<= 1) {
    int u = (threadIdx.x >= s) ? sm[threadIdx.x - s] : 0;
    __syncthreads();
    sm[threadIdx.x] += u;
    __syncthreads();
  }
  if (i < n) row_ptr[i] = bsum[blockIdx.x] + sm[threadIdx.x] - v;  // exclusive
}

__global__ void k_init_rows(const int* __restrict__ deg, const int* __restrict__ row_ptr,
                            int* __restrict__ cursor, int* __restrict__ col,
                            float* __restrict__ dinv, int n) {
  int i = blockIdx.x * blockDim.x + threadIdx.x;
  if (i < n) {
    int rp = row_ptr[i];
    col[rp] = i;          // self-loop entry first (deterministic)
    cursor[i] = rp + 1;
    dinv[i] = rsqrtf((float)(deg[i] + 1));
  }
}

__global__ void k_fill_edges(const int* __restrict__ src, const int* __restrict__ dst,
                             int* __restrict__ cursor, int* __restrict__ col, int E) {
  int e = blockIdx.x * blockDim.x + threadIdx.x;
  if (e < E) {
    int pos = atomicAdd(&cursor[dst[e]], 1);
    col[pos] = src[e];
  }
}

// -------- weight pre-split: W (K x N, fp32) -> Wt_hi/Wt_lo (N x Kp, bf16 bits) --------

__global__ void k_prep_w(const float* __restrict__ W, unsigned short* __restrict__ hi,
                         unsigned short* __restrict__ lo, int K, int N, int Kp) {
  int i = blockIdx.x * 256 + threadIdx.x;
  if (i >= N * Kp) return;
  int n = i / Kp, k = i % Kp;
  float v = (k < K) ? W[(size_t)k * N + n] : 0.f;
  unsigned short h = f2bf_rn(v);
  unsigned short l = f2bf_rn(v - bf2f(h));
  hi[i] = h;
  lo[i] = l;
}

// ---------------- aggregation: z = (1-a)*Ahat*h + a*h0 ----------------
// one wave per destination node; lane holds features (2*lane, 2*lane+1)

__global__ void __launch_bounds__(256) k_agg(
    const float* __restrict__ h, const float* __restrict__ h0, float* __restrict__ z,
    const int* __restrict__ row_ptr, const int* __restrict__ deg,
    const int* __restrict__ col, const float* __restrict__ dinv) {
  int wid = (blockIdx.x * blockDim.x + threadIdx.x) >> 6;
  int lane = threadIdx.x & 63;
  if (wid >= NN) return;
  int start = row_ptr[wid];
  int cnt = deg[wid] + 1;
  const float2* __restrict__ h2 = (const float2*)h;
  float ax = 0.f, ay = 0.f;
  int c = col[start];
  for (int i = 0; i < cnt; ++i) {
    int cn = (i + 1 < cnt) ? col[start + i + 1] : 0;  // prefetch next index
    float dc = dinv[c];
    float2 v = h2[(size_t)c * 64 + lane];
    ax = fmaf(dc, v.x, ax);
    ay = fmaf(dc, v.y, ay);
    c = cn;
  }
  float dr = dinv[wid] * 0.9f;  // (1-ALPHA) * dinv[dst]
  float2 r0 = ((const float2*)h0)[(size_t)wid * 64 + lane];
  float2 zo;
  zo.x = fmaf(dr, ax, 0.1f * r0.x);
  zo.y = fmaf(dr, ay, 0.1f * r0.y);
  ((float2*)z)[(size_t)wid * 64 + lane] = zo;
}

// ---------------- MFMA bf16x3 GEMM: C = epi(A @ B) ----------------
// A: M x K fp32.  B: pre-split hi/lo bf16, transposed [N][Kp].
// 128 x BN tile, 4 waves (2x2), each wave 64 x (BN/2) = 4 x NF fragments 16x16.
// EPI 0: relu(A@B + bias)   EPI 1: relu(p0*A + p1*(A@B))   EPI 2: A@B + bias

template <int BN, int EPI>
__global__ void __launch_bounds__(256) k_mgemm(
    const float* __restrict__ A, const unsigned short* __restrict__ Bhg,
    const unsigned short* __restrict__ Blg, const float* __restrict__ bias,
    float* __restrict__ C, int M, int K, int Kp, float p0, float p1) {
  constexpr int SK = 40;        // padded LDS row stride (bf16 elems): 80 B
  constexpr int NF = BN / 32;   // fragments per wave in N
  __shared__ __align__(16) unsigned short Ah[128 * SK];
  __shared__ __align__(16) unsigned short Al[128 * SK];
  __shared__ __align__(16) unsigned short Bh[BN * SK];
  __shared__ __align__(16) unsigned short Bl[BN * SK];
  int tid = threadIdx.x;
  int wid = tid >> 6, lane = tid & 63;
  int wr = wid >> 1, wc = wid & 1;
  int lr = lane & 15, kg = lane >> 4;
  int row0 = blockIdx.x * 128;

  f32x4 acc[4][NF];
#pragma unroll
  for (int m = 0; m < 4; ++m)
#pragma unroll
    for (int n = 0; n < NF; ++n) acc[m][n] = {0.f, 0.f, 0.f, 0.f};

  for (int kt = 0; kt < Kp; kt += 32) {
    // stage A: 128 rows x 32 k, fp32 -> hi/lo bf16
#pragma unroll
    for (int p = 0; p < 4; ++p) {
      int idx = tid + p * 256;
      int r = idx >> 3, kq = idx & 7;
      int gr = row0 + r, gk = kt + kq * 4;
      float4 v = make_float4(0.f, 0.f, 0.f, 0.f);
      if (gr < M && gk < K) v = *reinterpret_cast<const float4*>(&A[(size_t)gr * K + gk]);
      const float* vp = &v.x;
      s16x4 h4, l4;
#pragma unroll
      for (int e = 0; e < 4; ++e) {
        unsigned short h = f2bf_rn(vp[e]);
        h4[e] = (short)h;
        l4[e] = (short)f2bf_rn(vp[e] - bf2f(h));
      }
      *reinterpret_cast<s16x4*>(&Ah[r * SK + kq * 4]) = h4;
      *reinterpret_cast<s16x4*>(&Al[r * SK + kq * 4]) = l4;
    }
    // stage B: BN cols x 32 k, straight copy of pre-split weights
#pragma unroll
    for (int p = 0; p < BN / 64; ++p) {
      int idx = tid + p * 256;
      int n = idx >> 2, kq8 = idx & 3;
      size_t so = (size_t)n * Kp + kt + kq8 * 8;
      *reinterpret_cast<s16x8*>(&Bh[n * SK + kq8 * 8]) =
          *reinterpret_cast<const s16x8*>(&Bhg[so]);
      *reinterpret_cast<s16x8*>(&Bl[n * SK + kq8 * 8]) =
          *reinterpret_cast<const s16x8*>(&Blg[so]);
    }
    __syncthreads();

    bf16x8 afh[4], afl[4], bfh[NF], bfl[NF];
#pragma unroll
    for (int m = 0; m < 4; ++m) {
      int r = wr * 64 + m * 16 + lr;
      afh[m] = *reinterpret_cast<const bf16x8*>(&Ah[r * SK + kg * 8]);
      afl[m] = *reinterpret_cast<const bf16x8*>(&Al[r * SK + kg * 8]);
    }
#pragma unroll
    for (int n = 0; n < NF; ++n) {
      int c = wc * (NF * 16) + n * 16 + lr;
      bfh[n] = *reinterpret_cast<const bf16x8*>(&Bh[c * SK + kg * 8]);
      bfl[n] = *reinterpret_cast<const bf16x8*>(&Bl[c * SK + kg * 8]);
    }
#pragma unroll
    for (int m = 0; m < 4; ++m)
#pragma unroll
      for (int n = 0; n < NF; ++n) {
        acc[m][n] = __builtin_amdgcn_mfma_f32_16x16x32_bf16(afh[m], bfh[n], acc[m][n], 0, 0, 0);
        acc[m][n] = __builtin_amdgcn_mfma_f32_16x16x32_bf16(afl[m], bfh[n], acc[m][n], 0, 0, 0);
        acc[m][n] = __builtin_amdgcn_mfma_f32_16x16x32_bf16(afh[m], bfl[n], acc[m][n], 0, 0, 0);
      }
    __syncthreads();
  }

  // epilogue: C/D layout col = lane&15, row = (lane>>4)*4 + reg
#pragma unroll
  for (int m = 0; m < 4; ++m) {
#pragma unroll
    for (int n = 0; n < NF; ++n) {
      int gc = wc * (NF * 16) + n * 16 + lr;
#pragma unroll
      for (int q = 0; q < 4; ++q) {
        int gr = row0 + wr * 64 + m * 16 + kg * 4 + q;
        if (gr < M) {
          float v = acc[m][n][q];
          if (EPI == 0)      v = fmaxf(v + bias[gc], 0.f);
          else if (EPI == 1) v = fmaxf(fmaf(p0, A[(size_t)gr * K + gc], p1 * v), 0.f);
          else               v += bias[gc];
          C[(size_t)gr * BN + gc] = v;
        }
      }
    }
  }
}

// ---------------- launch ----------------

extern "C" void kernel_launch(void* const* d_in, const int* in_sizes, int n_in,
                              void* d_out, int out_size, void* d_ws, size_t ws_size,
                              hipStream_t stream) {
  const float* x     = (const float*)d_in[0];
  const int*   ei    = (const int*)d_in[1];
  const float* W_in  = (const float*)d_in[2];
  const float* b_in  = (const float*)d_in[3];
  const float* W_cv  = (const float*)d_in[4];
  const float* W_out = (const float*)d_in[5];
  const float* b_out = (const float*)d_in[6];
  float* out = (float*)d_out;

  char* ws = (char*)d_ws;
  size_t off = 0;
  auto alloc = [&](size_t bytes) {
    char* p = ws + off;
    off = (off + bytes + 255) & ~(size_t)255;
    return p;
  };
  int*   deg     = (int*)alloc((size_t)NN * 4);
  int*   row_ptr = (int*)alloc((size_t)NN * 4);
  int*   cursor  = (int*)alloc((size_t)NN * 4);
  int*   bsum    = (int*)alloc(512 * 4);
  float* dinv    = (float*)alloc((size_t)NN * 4);
  int*   col     = (int*)alloc((size_t)(EE + NN) * 4);
  float* h0      = (float*)alloc((size_t)NN * HIDC * 4);
  float* zb      = (float*)alloc((size_t)NN * HIDC * 4);
  float* hb      = (float*)alloc((size_t)NN * HIDC * 4);
  unsigned short* win_h  = (unsigned short*)alloc((size_t)HIDC * 512 * 2);
  unsigned short* win_l  = (unsigned short*)alloc((size_t)HIDC * 512 * 2);
  unsigned short* wcv_h  = (unsigned short*)alloc((size_t)NLAYER * HIDC * HIDC * 2);
  unsigned short* wcv_l  = (unsigned short*)alloc((size_t)NLAYER * HIDC * HIDC * 2);
  unsigned short* wout_h = (unsigned short*)alloc((size_t)OUTC * HIDC * 2);
  unsigned short* wout_l = (unsigned short*)alloc((size_t)OUTC * HIDC * 2);

  const int* srcp = ei;
  const int* dstp = ei + EE;

  hipMemsetAsync(deg, 0, (size_t)NN * 4, stream);
  k_count_deg<<<(EE + 255) / 256, 256, 0, stream>>>(dstp, deg, EE);
  int nb = (NN + 255) / 256;  // 391 <= 512
  k_scan_block_sums<<<nb, 256, 0, stream>>>(deg, bsum, NN);
  k_scan_partials<<<1, 512, 0, stream>>>(bsum, nb);
  k_scan_final<<<nb, 256, 0, stream>>>(deg, bsum, row_ptr, NN);
  k_init_rows<<<(NN + 255) / 256, 256, 0, stream>>>(deg, row_ptr, cursor, col, dinv, NN);
  k_fill_edges<<<(EE + 255) / 256, 256, 0, stream>>>(srcp, dstp, cursor, col, EE);

  // pre-split weights into transposed hi/lo bf16
  k_prep_w<<<(HIDC * 512 + 255) / 256, 256, 0, stream>>>(W_in, win_h, win_l, INC, HIDC, 512);
  for (int l = 0; l < NLAYER; ++l)
    k_prep_w<<<(HIDC * HIDC + 255) / 256, 256, 0, stream>>>(
        W_cv + (size_t)l * HIDC * HIDC, wcv_h + (size_t)l * HIDC * HIDC,
        wcv_l + (size_t)l * HIDC * HIDC, HIDC, HIDC, HIDC);
  k_prep_w<<<(OUTC * HIDC + 255) / 256, 256, 0, stream>>>(W_out, wout_h, wout_l, HIDC, OUTC, HIDC);

  int gblk = (NN + 127) / 128;
  // h0 = relu(x @ W_in + b_in)
  k_mgemm<128, 0><<<gblk, 256, 0, stream>>>(x, win_h, win_l, b_in, h0, NN, INC, 512, 0.f, 0.f);

  const float* hcur = h0;
  for (int l = 0; l < NLAYER; ++l) {
    k_agg<<<((size_t)NN * 64 + 255) / 256, 256, 0, stream>>>(hcur, h0, zb, row_ptr, deg, col, dinv);
    float beta = logf(0.5f / (float)(l + 1) + 1.0f);
    // h = relu((1-beta)*z + beta*(z @ W_conv[l]))
    k_mgemm<128, 1><<<gblk, 256, 0, stream>>>(zb, wcv_h + (size_t)l * HIDC * HIDC,
                                              wcv_l + (size_t)l * HIDC * HIDC, nullptr, hb,
                                              NN, HIDC, HIDC, 1.0f - beta, beta);
    hcur = hb;
  }
  // out = h @ W_out + b_out
  k_mgemm<64, 2><<<gblk, 256, 0, stream>>>(hcur, wout_h, wout_l, b_out, out, NN, HIDC, HIDC, 0.f, 0.f);
}

// Round 4
// 2119.208 us; speedup vs baseline: 1.3280x; 1.0614x over previous
//
#include <hip/hip_runtime.h>
#include <hip/hip_fp16.h>
#include <cmath>

#define NN 100000
#define EE 1600000
#define INC 500
#define HIDC 128
#define OUTC 64
#define NLAYER 8

typedef float f32x4 __attribute__((ext_vector_type(4)));
typedef __bf16 bf16x8 __attribute__((ext_vector_type(8)));
typedef short s16x4 __attribute__((ext_vector_type(4)));
typedef short s16x8 __attribute__((ext_vector_type(8)));

__device__ __forceinline__ unsigned short f2bf_rn(float f) {
  unsigned u = __float_as_uint(f);
  unsigned r = u + 0x7fffu + ((u >> 16) & 1u);
  return (unsigned short)(r >> 16);
}
__device__ __forceinline__ float bf2f(unsigned short h) {
  return __uint_as_float(((unsigned)h) << 16);
}

// ---------------- graph preprocessing ----------------

__global__ void k_count_deg(const int* __restrict__ dst, int* __restrict__ deg, int E) {
  int e = blockIdx.x * blockDim.x + threadIdx.x;
  if (e < E) atomicAdd(&deg[dst[e]], 1);
}

__global__ void k_scan_block_sums(const int* __restrict__ deg, int* __restrict__ bsum, int n) {
  __shared__ int sm[256];
  int i = blockIdx.x * 256 + threadIdx.x;
  int v = (i < n) ? deg[i] + 1 : 0;  // +1 for self-loop
  sm[threadIdx.x] = v;
  __syncthreads();
  for (int s = 128; s > 0; s >>= 1) {
    if (threadIdx.x < s) sm[threadIdx.x] += sm[threadIdx.x + s];
    __syncthreads();
  }
  if (threadIdx.x == 0) bsum[blockIdx.x] = sm[0];
}

__global__ void k_scan_partials(int* __restrict__ bsum, int nb) {
  __shared__ int sm[512];
  int t = threadIdx.x;
  sm[t] = (t < nb) ? bsum[t] : 0;
  __syncthreads();
  for (int s = 1; s < 512; s <<= 1) {
    int v = (t >= s) ? sm[t - s] : 0;
    __syncthreads();
    sm[t] += v;
    __syncthreads();
  }
  if (t < nb) bsum[t] = (t == 0) ? 0 : sm[t - 1];  // exclusive
}

__global__ void k_scan_final(const int* __restrict__ deg, const int* __restrict__ bsum,
                             int* __restrict__ row_ptr, int n) {
  __shared__ int sm[256];
  int i = blockIdx.x * 256 + threadIdx.x;
  int v = (i < n) ? deg[i] + 1 : 0;
  sm[threadIdx.x] = v;
  __syncthreads();
  for (int s = 1; s < 256; s <<= 1) {
    int u = (threadIdx.x >= s) ? sm[threadIdx.x - s] : 0;
    __syncthreads();
    sm[threadIdx.x] += u;
    __syncthreads();
  }
  if (i < n) row_ptr[i] = bsum[blockIdx.x] + sm[threadIdx.x] - v;  // exclusive
}

__global__ void k_init_rows(const int* __restrict__ deg, const int* __restrict__ row_ptr,
                            int* __restrict__ cursor, int* __restrict__ col,
                            float* __restrict__ dinv, int n) {
  int i = blockIdx.x * blockDim.x + threadIdx.x;
  if (i < n) {
    int rp = row_ptr[i];
    col[rp] = i;          // self-loop entry first (deterministic)
    cursor[i] = rp + 1;
    dinv[i] = rsqrtf((float)(deg[i] + 1));
  }
}

__global__ void k_fill_edges(const int* __restrict__ src, const int* __restrict__ dst,
                             int* __restrict__ cursor, int* __restrict__ col, int E) {
  int e = blockIdx.x * blockDim.x + threadIdx.x;
  if (e < E) {
    int pos = atomicAdd(&cursor[dst[e]], 1);
    col[pos] = src[e];
  }
}

// -------- weight pre-split: W (K x N, fp32) -> Wt_hi/Wt_lo (N x Kp, bf16 bits) --------

__global__ void k_prep_w(const float* __restrict__ W, unsigned short* __restrict__ hi,
                         unsigned short* __restrict__ lo, int K, int N, int Kp) {
  int i = blockIdx.x * 256 + threadIdx.x;
  if (i >= N * Kp) return;
  int n = i / Kp, k = i % Kp;
  float v = (k < K) ? W[(size_t)k * N + n] : 0.f;
  unsigned short h = f2bf_rn(v);
  unsigned short l = f2bf_rn(v - bf2f(h));
  hi[i] = h;
  lo[i] = l;
}

// ---------------- aggregation: z = 0.9*dinv_dst*sum(h'_src) + 0.1*h0 ----------------
// h' = dinv*h pre-scaled fp16. One wave per dst node; lane holds features (2l, 2l+1).

__global__ void __launch_bounds__(256) k_agg(
    const __half* __restrict__ hs, const __half* __restrict__ h0u, float* __restrict__ z,
    const int* __restrict__ row_ptr, const int* __restrict__ deg,
    const int* __restrict__ col, const float* __restrict__ dinv) {
  int wid = (blockIdx.x * blockDim.x + threadIdx.x) >> 6;
  int lane = threadIdx.x & 63;
  if (wid >= NN) return;
  int start = row_ptr[wid];
  int cnt = deg[wid] + 1;
  const __half2* __restrict__ h2 = (const __half2*)hs;
  float ax = 0.f, ay = 0.f;
  __half2 v = h2[(size_t)col[start] * 64 + lane];
  for (int i = 0; i < cnt; ++i) {
    __half2 vc = v;
    if (i + 1 < cnt) {
      int cn = col[start + i + 1];
      v = h2[(size_t)cn * 64 + lane];  // prefetch next row
    }
    float2 f = __half22float2(vc);
    ax += f.x;
    ay += f.y;
  }
  float dr = dinv[wid] * 0.9f;
  float2 f0 = __half22float2(((const __half2*)h0u)[(size_t)wid * 64 + lane]);
  float2 zo;
  zo.x = fmaf(dr, ax, 0.1f * f0.x);
  zo.y = fmaf(dr, ay, 0.1f * f0.y);
  ((float2*)z)[(size_t)wid * 64 + lane] = zo;
}

// ---------------- MFMA bf16x3 GEMM: C = epi(A @ B) ----------------
// A: M x K fp32.  B: pre-split hi/lo bf16, transposed [N][Kp].
// 128 x BN tile, 4 waves (2x2), each wave 64 x (BN/2) = 4 x NF fragments 16x16.
// EPI 0: relu(A@B + bias) -> fp16 unscaled + fp16 scaled   (input projection)
// EPI 1: relu(p0*A + p1*(A@B)) -> fp16 scaled              (mid layer)
// EPI 3: relu(p0*A + p1*(A@B)) -> fp32                     (last layer)
// EPI 2: A@B + bias -> fp32                                (output projection)

template <int BN, int EPI>
__global__ void __launch_bounds__(256) k_mgemm(
    const float* __restrict__ A, const unsigned short* __restrict__ Bhg,
    const unsigned short* __restrict__ Blg, const float* __restrict__ bias,
    float* __restrict__ C, __half* __restrict__ C16u, __half* __restrict__ C16s,
    const float* __restrict__ dinv, int M, int K, int Kp, float p0, float p1) {
  constexpr int SK = 40;        // padded LDS row stride (bf16 elems): 80 B
  constexpr int NF = BN / 32;   // fragments per wave in N
  __shared__ __align__(16) unsigned short Ah[128 * SK];
  __shared__ __align__(16) unsigned short Al[128 * SK];
  __shared__ __align__(16) unsigned short Bh[BN * SK];
  __shared__ __align__(16) unsigned short Bl[BN * SK];
  int tid = threadIdx.x;
  int wid = tid >> 6, lane = tid & 63;
  int wr = wid >> 1, wc = wid & 1;
  int lr = lane & 15, kg = lane >> 4;
  int row0 = blockIdx.x * 128;

  f32x4 acc[4][NF];
#pragma unroll
  for (int m = 0; m < 4; ++m)
#pragma unroll
    for (int n = 0; n < NF; ++n) acc[m][n] = {0.f, 0.f, 0.f, 0.f};

  for (int kt = 0; kt < Kp; kt += 32) {
    // stage A: 128 rows x 32 k, fp32 -> hi/lo bf16
#pragma unroll
    for (int p = 0; p < 4; ++p) {
      int idx = tid + p * 256;
      int r = idx >> 3, kq = idx & 7;
      int gr = row0 + r, gk = kt + kq * 4;
      float4 v = make_float4(0.f, 0.f, 0.f, 0.f);
      if (gr < M && gk < K) v = *reinterpret_cast<const float4*>(&A[(size_t)gr * K + gk]);
      const float* vp = &v.x;
      s16x4 h4, l4;
#pragma unroll
      for (int e = 0; e < 4; ++e) {
        unsigned short h = f2bf_rn(vp[e]);
        h4[e] = (short)h;
        l4[e] = (short)f2bf_rn(vp[e] - bf2f(h));
      }
      *reinterpret_cast<s16x4*>(&Ah[r * SK + kq * 4]) = h4;
      *reinterpret_cast<s16x4*>(&Al[r * SK + kq * 4]) = l4;
    }
    // stage B: BN cols x 32 k, straight copy of pre-split weights
#pragma unroll
    for (int p = 0; p < BN / 64; ++p) {
      int idx = tid + p * 256;
      int n = idx >> 2, kq8 = idx & 3;
      size_t so = (size_t)n * Kp + kt + kq8 * 8;
      *reinterpret_cast<s16x8*>(&Bh[n * SK + kq8 * 8]) =
          *reinterpret_cast<const s16x8*>(&Bhg[so]);
      *reinterpret_cast<s16x8*>(&Bl[n * SK + kq8 * 8]) =
          *reinterpret_cast<const s16x8*>(&Blg[so]);
    }
    __syncthreads();

    bf16x8 afh[4], afl[4], bfh[NF], bfl[NF];
#pragma unroll
    for (int m = 0; m < 4; ++m) {
      int r = wr * 64 + m * 16 + lr;
      afh[m] = *reinterpret_cast<const bf16x8*>(&Ah[r * SK + kg * 8]);
      afl[m] = *reinterpret_cast<const bf16x8*>(&Al[r * SK + kg * 8]);
    }
#pragma unroll
    for (int n = 0; n < NF; ++n) {
      int c = wc * (NF * 16) + n * 16 + lr;
      bfh[n] = *reinterpret_cast<const bf16x8*>(&Bh[c * SK + kg * 8]);
      bfl[n] = *reinterpret_cast<const bf16x8*>(&Bl[c * SK + kg * 8]);
    }
#pragma unroll
    for (int m = 0; m < 4; ++m)
#pragma unroll
      for (int n = 0; n < NF; ++n) {
        acc[m][n] = __builtin_amdgcn_mfma_f32_16x16x32_bf16(afh[m], bfh[n], acc[m][n], 0, 0, 0);
        acc[m][n] = __builtin_amdgcn_mfma_f32_16x16x32_bf16(afl[m], bfh[n], acc[m][n], 0, 0, 0);
        acc[m][n] = __builtin_amdgcn_mfma_f32_16x16x32_bf16(afh[m], bfl[n], acc[m][n], 0, 0, 0);
      }
    __syncthreads();
  }

  // epilogue: C/D layout col = lane&15, row = (lane>>4)*4 + reg
#pragma unroll
  for (int m = 0; m < 4; ++m) {
#pragma unroll
    for (int n = 0; n < NF; ++n) {
      int gc = wc * (NF * 16) + n * 16 + lr;
#pragma unroll
      for (int q = 0; q < 4; ++q) {
        int gr = row0 + wr * 64 + m * 16 + kg * 4 + q;
        if (gr < M) {
          float v = acc[m][n][q];
          if (EPI == 0) {
            v = fmaxf(v + bias[gc], 0.f);
            C16u[(size_t)gr * BN + gc] = __float2half(v);
            C16s[(size_t)gr * BN + gc] = __float2half(v * dinv[gr]);
          } else if (EPI == 1) {
            v = fmaxf(fmaf(p0, A[(size_t)gr * K + gc], p1 * v), 0.f);
            C16s[(size_t)gr * BN + gc] = __float2half(v * dinv[gr]);
          } else if (EPI == 3) {
            v = fmaxf(fmaf(p0, A[(size_t)gr * K + gc], p1 * v), 0.f);
            C[(size_t)gr * BN + gc] = v;
          } else {
            C[(size_t)gr * BN + gc] = v + bias[gc];
          }
        }
      }
    }
  }
}

// ---------------- launch ----------------

extern "C" void kernel_launch(void* const* d_in, const int* in_sizes, int n_in,
                              void* d_out, int out_size, void* d_ws, size_t ws_size,
                              hipStream_t stream) {
  const float* x     = (const float*)d_in[0];
  const int*   ei    = (const int*)d_in[1];
  const float* W_in  = (const float*)d_in[2];
  const float* b_in  = (const float*)d_in[3];
  const float* W_cv  = (const float*)d_in[4];
  const float* W_out = (const float*)d_in[5];
  const float* b_out = (const float*)d_in[6];
  float* out = (float*)d_out;

  char* ws = (char*)d_ws;
  size_t off = 0;
  auto alloc = [&](size_t bytes) {
    char* p = ws + off;
    off = (off + bytes + 255) & ~(size_t)255;
    return p;
  };
  int*    deg     = (int*)alloc((size_t)NN * 4);
  int*    row_ptr = (int*)alloc((size_t)NN * 4);
  int*    cursor  = (int*)alloc((size_t)NN * 4);
  int*    bsum    = (int*)alloc(512 * 4);
  float*  dinv    = (float*)alloc((size_t)NN * 4);
  int*    col     = (int*)alloc((size_t)(EE + NN) * 4);
  __half* h016u   = (__half*)alloc((size_t)NN * HIDC * 2);
  __half* h016s   = (__half*)alloc((size_t)NN * HIDC * 2);
  __half* hsA     = (__half*)alloc((size_t)NN * HIDC * 2);
  __half* hsB     = (__half*)alloc((size_t)NN * HIDC * 2);
  float*  zb      = (float*)alloc((size_t)NN * HIDC * 4);
  float*  hb      = (float*)alloc((size_t)NN * HIDC * 4);
  unsigned short* win_h  = (unsigned short*)alloc((size_t)HIDC * 512 * 2);
  unsigned short* win_l  = (unsigned short*)alloc((size_t)HIDC * 512 * 2);
  unsigned short* wcv_h  = (unsigned short*)alloc((size_t)NLAYER * HIDC * HIDC * 2);
  unsigned short* wcv_l  = (unsigned short*)alloc((size_t)NLAYER * HIDC * HIDC * 2);
  unsigned short* wout_h = (unsigned short*)alloc((size_t)OUTC * HIDC * 2);
  unsigned short* wout_l = (unsigned short*)alloc((size_t)OUTC * HIDC * 2);

  const int* srcp = ei;
  const int* dstp = ei + EE;

  hipMemsetAsync(deg, 0, (size_t)NN * 4, stream);
  k_count_deg<<<(EE + 255) / 256, 256, 0, stream>>>(dstp, deg, EE);
  int nb = (NN + 255) / 256;  // 391 <= 512
  k_scan_block_sums<<<nb, 256, 0, stream>>>(deg, bsum, NN);
  k_scan_partials<<<1, 512, 0, stream>>>(bsum, nb);
  k_scan_final<<<nb, 256, 0, stream>>>(deg, bsum, row_ptr, NN);
  k_init_rows<<<(NN + 255) / 256, 256, 0, stream>>>(deg, row_ptr, cursor, col, dinv, NN);
  k_fill_edges<<<(EE + 255) / 256, 256, 0, stream>>>(srcp, dstp, cursor, col, EE);

  // pre-split weights into transposed hi/lo bf16
  k_prep_w<<<(HIDC * 512 + 255) / 256, 256, 0, stream>>>(W_in, win_h, win_l, INC, HIDC, 512);
  for (int l = 0; l < NLAYER; ++l)
    k_prep_w<<<(HIDC * HIDC + 255) / 256, 256, 0, stream>>>(
        W_cv + (size_t)l * HIDC * HIDC, wcv_h + (size_t)l * HIDC * HIDC,
        wcv_l + (size_t)l * HIDC * HIDC, HIDC, HIDC, HIDC);
  k_prep_w<<<(OUTC * HIDC + 255) / 256, 256, 0, stream>>>(W_out, wout_h, wout_l, HIDC, OUTC, HIDC);

  int gblk = (NN + 127) / 128;
  // h0 = relu(x @ W_in + b_in) -> fp16 unscaled + scaled
  k_mgemm<128, 0><<<gblk, 256, 0, stream>>>(x, win_h, win_l, b_in, nullptr, h016u, h016s,
                                            dinv, NN, INC, 512, 0.f, 0.f);

  const __half* hcur = h016s;
  for (int l = 0; l < NLAYER; ++l) {
    k_agg<<<((size_t)NN * 64 + 255) / 256, 256, 0, stream>>>(hcur, h016u, zb, row_ptr, deg, col, dinv);
    float beta = logf(0.5f / (float)(l + 1) + 1.0f);
    const unsigned short* wh = wcv_h + (size_t)l * HIDC * HIDC;
    const unsigned short* wl = wcv_l + (size_t)l * HIDC * HIDC;
    if (l < NLAYER - 1) {
      __half* tgt = (l & 1) ? hsB : hsA;
      k_mgemm<128, 1><<<gblk, 256, 0, stream>>>(zb, wh, wl, nullptr, nullptr, nullptr, tgt,
                                                dinv, NN, HIDC, HIDC, 1.0f - beta, beta);
      hcur = tgt;
    } else {
      k_mgemm<128, 3><<<gblk, 256, 0, stream>>>(zb, wh, wl, nullptr, hb, nullptr, nullptr,
                                                dinv, NN, HIDC, HIDC, 1.0f - beta, beta);
    }
  }
  // out = h @ W_out + b_out
  k_mgemm<64, 2><<<gblk, 256, 0, stream>>>(hb, wout_h, wout_l, b_out, out, nullptr, nullptr,
                                           dinv, NN, HIDC, HIDC, 0.f, 0.f);
}

// Round 5
// 1412.645 us; speedup vs baseline: 1.9922x; 1.5002x over previous
//
#include <hip/hip_runtime.h>
#include <hip/hip_fp16.h>
#include <cmath>

#define NN 100000
#define EE 1600000
#define INC 500
#define HIDC 128
#define OUTC 64
#define NLAYER 8

typedef float f32x4 __attribute__((ext_vector_type(4)));
typedef __bf16 bf16x8 __attribute__((ext_vector_type(8)));
typedef short s16x4 __attribute__((ext_vector_type(4)));
typedef short s16x8 __attribute__((ext_vector_type(8)));

__device__ __forceinline__ unsigned short f2bf_rn(float f) {
  unsigned u = __float_as_uint(f);
  unsigned r = u + 0x7fffu + ((u >> 16) & 1u);
  return (unsigned short)(r >> 16);
}
__device__ __forceinline__ float bf2f(unsigned short h) {
  return __uint_as_float(((unsigned)h) << 16);
}

// ---------------- graph preprocessing ----------------

__global__ void k_count_deg(const int* __restrict__ dst, int* __restrict__ deg, int E) {
  int e = blockIdx.x * blockDim.x + threadIdx.x;
  if (e < E) atomicAdd(&deg[dst[e]], 1);
}

__global__ void k_scan_block_sums(const int* __restrict__ deg, int* __restrict__ bsum, int n) {
  __shared__ int sm[256];
  int i = blockIdx.x * 256 + threadIdx.x;
  int v = (i < n) ? deg[i] + 1 : 0;  // +1 for self-loop
  sm[threadIdx.x] = v;
  __syncthreads();
  for (int s = 128; s > 0; s >>= 1) {
    if (threadIdx.x < s) sm[threadIdx.x] += sm[threadIdx.x + s];
    __syncthreads();
  }
  if (threadIdx.x == 0) bsum[blockIdx.x] = sm[0];
}

__global__ void k_scan_partials(int* __restrict__ bsum, int nb) {
  __shared__ int sm[512];
  int t = threadIdx.x;
  sm[t] = (t < nb) ? bsum[t] : 0;
  __syncthreads();
  for (int s = 1; s < 512; s <<= 1) {
    int v = (t >= s) ? sm[t - s] : 0;
    __syncthreads();
    sm[t] += v;
    __syncthreads();
  }
  if (t < nb) bsum[t] = (t == 0) ? 0 : sm[t - 1];  // exclusive
}

__global__ void k_scan_final(const int* __restrict__ deg, const int* __restrict__ bsum,
                             int* __restrict__ row_ptr, int n) {
  __shared__ int sm[256];
  int i = blockIdx.x * 256 + threadIdx.x;
  int v = (i < n) ? deg[i] + 1 : 0;
  sm[threadIdx.x] = v;
  __syncthreads();
  for (int s = 1; s < 256; s <<= 1) {
    int u = (threadIdx.x >= s) ? sm[threadIdx.x - s] : 0;
    __syncthreads();
    sm[threadIdx.x] += u;
    __syncthreads();
  }
  if (i < n) row_ptr[i] = bsum[blockIdx.x] + sm[threadIdx.x] - v;  // exclusive
}

__global__ void k_init_rows(const int* __restrict__ deg, const int* __restrict__ row_ptr,
                            int* __restrict__ cursor, int* __restrict__ col,
                            float* __restrict__ dinv, int n) {
  int i = blockIdx.x * blockDim.x + threadIdx.x;
  if (i < n) {
    int rp = row_ptr[i];
    col[rp] = i;          // self-loop entry first (deterministic)
    cursor[i] = rp + 1;
    dinv[i] = rsqrtf((float)(deg[i] + 1));
  }
}

__global__ void k_fill_edges(const int* __restrict__ src, const int* __restrict__ dst,
                             int* __restrict__ cursor, int* __restrict__ col, int E) {
  int e = blockIdx.x * blockDim.x + threadIdx.x;
  if (e < E) {
    int pos = atomicAdd(&cursor[dst[e]], 1);
    col[pos] = src[e];
  }
}

// -------- weight pre-split: W (K x N, fp32) -> Wt_hi/Wt_lo (N x Kp, bf16 bits) --------

__global__ void k_prep_w(const float* __restrict__ W, unsigned short* __restrict__ hi,
                         unsigned short* __restrict__ lo, int K, int N, int Kp) {
  int i = blockIdx.x * 256 + threadIdx.x;
  if (i >= N * Kp) return;
  int n = i / Kp, k = i % Kp;
  float v = (k < K) ? W[(size_t)k * N + n] : 0.f;
  unsigned short h = f2bf_rn(v);
  unsigned short l = f2bf_rn(v - bf2f(h));
  hi[i] = h;
  lo[i] = l;
}

// ---------------- aggregation: z = 0.9*dinv_dst*sum(h'_src) + 0.1*h0 ----------------
// h' = dinv*h pre-scaled fp16. One wave per dst node. 4 lane-groups of 16;
// group g handles edge chunk slot g, lane loads 16B (8 fp16 features).
// 2-deep double buffer -> up to 8 rows (2KB) in flight per wave.

__global__ void __launch_bounds__(256) k_agg(
    const __half* __restrict__ hs, const __half* __restrict__ h0u, float* __restrict__ z,
    const int* __restrict__ row_ptr, const int* __restrict__ deg,
    const int* __restrict__ col, const float* __restrict__ dinv) {
  int wid = (blockIdx.x * blockDim.x + threadIdx.x) >> 6;
  int lane = threadIdx.x & 63;
  if (wid >= NN) return;
  int g = lane >> 4;    // edge slot within chunk
  int fl = lane & 15;   // feature sub-lane: features [8*fl, 8*fl+8)
  int start = row_ptr[wid];
  int cnt = deg[wid] + 1;
  int nch = (cnt + 3) >> 2;

  float acc[8];
#pragma unroll
  for (int j = 0; j < 8; ++j) acc[j] = 0.f;

  auto load_chunk = [&](int ch, s16x8& v, float& m) {
    int e = ch * 4 + g;
    bool valid = e < cnt;
    int c = col[start + (valid ? e : 0)];
    m = valid ? 1.f : 0.f;
    v = *reinterpret_cast<const s16x8*>(&hs[(size_t)c * HIDC + fl * 8]);
  };

  s16x8 curv; float curm;
  load_chunk(0, curv, curm);
  for (int ch = 0; ch < nch; ++ch) {
    s16x8 nv = {}; float nm = 0.f;
    if (ch + 1 < nch) load_chunk(ch + 1, nv, nm);
    const __half2* hp = reinterpret_cast<const __half2*>(&curv);
#pragma unroll
    for (int j = 0; j < 4; ++j) {
      float2 f = __half22float2(hp[j]);
      acc[2 * j]     = fmaf(curm, f.x, acc[2 * j]);
      acc[2 * j + 1] = fmaf(curm, f.y, acc[2 * j + 1]);
    }
    curv = nv; curm = nm;
  }

  // combine the 4 group-partials: butterfly over lane bits 4..5
#pragma unroll
  for (int j = 0; j < 8; ++j) {
    acc[j] += __shfl_xor(acc[j], 16, 64);
    acc[j] += __shfl_xor(acc[j], 32, 64);
  }

  if (g == 0) {
    float dr = dinv[wid] * 0.9f;
    s16x8 r0 = *reinterpret_cast<const s16x8*>(&h0u[(size_t)wid * HIDC + fl * 8]);
    const __half2* r0p = reinterpret_cast<const __half2*>(&r0);
    float o[8];
#pragma unroll
    for (int j = 0; j < 4; ++j) {
      float2 f0 = __half22float2(r0p[j]);
      o[2 * j]     = fmaf(dr, acc[2 * j],     0.1f * f0.x);
      o[2 * j + 1] = fmaf(dr, acc[2 * j + 1], 0.1f * f0.y);
    }
    float* zp = &z[(size_t)wid * HIDC + fl * 8];
    *reinterpret_cast<float4*>(zp)     = make_float4(o[0], o[1], o[2], o[3]);
    *reinterpret_cast<float4*>(zp + 4) = make_float4(o[4], o[5], o[6], o[7]);
  }
}

// ---------------- MFMA bf16x3 GEMM: C = epi(A @ B) ----------------
// A: M x K fp32.  B: pre-split hi/lo bf16, transposed [N][Kp].
// 128 x BN tile, 4 waves (2x2), each wave 64 x (BN/2) = 4 x NF fragments 16x16.
// EPI 0: relu(A@B + bias) -> fp16 unscaled + fp16 scaled   (input projection)
// EPI 1: relu(p0*A + p1*(A@B)) -> fp16 scaled              (mid layer)
// EPI 3: relu(p0*A + p1*(A@B)) -> fp32                     (last layer)
// EPI 2: A@B + bias -> fp32                                (output projection)

template <int BN, int EPI>
__global__ void __launch_bounds__(256) k_mgemm(
    const float* __restrict__ A, const unsigned short* __restrict__ Bhg,
    const unsigned short* __restrict__ Blg, const float* __restrict__ bias,
    float* __restrict__ C, __half* __restrict__ C16u, __half* __restrict__ C16s,
    const float* __restrict__ dinv, int M, int K, int Kp, float p0, float p1) {
  constexpr int SK = 40;        // padded LDS row stride (bf16 elems): 80 B
  constexpr int NF = BN / 32;   // fragments per wave in N
  __shared__ __align__(16) unsigned short Ah[128 * SK];
  __shared__ __align__(16) unsigned short Al[128 * SK];
  __shared__ __align__(16) unsigned short Bh[BN * SK];
  __shared__ __align__(16) unsigned short Bl[BN * SK];
  int tid = threadIdx.x;
  int wid = tid >> 6, lane = tid & 63;
  int wr = wid >> 1, wc = wid & 1;
  int lr = lane & 15, kg = lane >> 4;
  int row0 = blockIdx.x * 128;

  f32x4 acc[4][NF];
#pragma unroll
  for (int m = 0; m < 4; ++m)
#pragma unroll
    for (int n = 0; n < NF; ++n) acc[m][n] = {0.f, 0.f, 0.f, 0.f};

  for (int kt = 0; kt < Kp; kt += 32) {
    // stage A: 128 rows x 32 k, fp32 -> hi/lo bf16
#pragma unroll
    for (int p = 0; p < 4; ++p) {
      int idx = tid + p * 256;
      int r = idx >> 3, kq = idx & 7;
      int gr = row0 + r, gk = kt + kq * 4;
      float4 v = make_float4(0.f, 0.f, 0.f, 0.f);
      if (gr < M && gk < K) v = *reinterpret_cast<const float4*>(&A[(size_t)gr * K + gk]);
      const float* vp = &v.x;
      s16x4 h4, l4;
#pragma unroll
      for (int e = 0; e < 4; ++e) {
        unsigned short h = f2bf_rn(vp[e]);
        h4[e] = (short)h;
        l4[e] = (short)f2bf_rn(vp[e] - bf2f(h));
      }
      *reinterpret_cast<s16x4*>(&Ah[r * SK + kq * 4]) = h4;
      *reinterpret_cast<s16x4*>(&Al[r * SK + kq * 4]) = l4;
    }
    // stage B: BN cols x 32 k, straight copy of pre-split weights
#pragma unroll
    for (int p = 0; p < BN / 64; ++p) {
      int idx = tid + p * 256;
      int n = idx >> 2, kq8 = idx & 3;
      size_t so = (size_t)n * Kp + kt + kq8 * 8;
      *reinterpret_cast<s16x8*>(&Bh[n * SK + kq8 * 8]) =
          *reinterpret_cast<const s16x8*>(&Bhg[so]);
      *reinterpret_cast<s16x8*>(&Bl[n * SK + kq8 * 8]) =
          *reinterpret_cast<const s16x8*>(&Blg[so]);
    }
    __syncthreads();

    bf16x8 afh[4], afl[4], bfh[NF], bfl[NF];
#pragma unroll
    for (int m = 0; m < 4; ++m) {
      int r = wr * 64 + m * 16 + lr;
      afh[m] = *reinterpret_cast<const bf16x8*>(&Ah[r * SK + kg * 8]);
      afl[m] = *reinterpret_cast<const bf16x8*>(&Al[r * SK + kg * 8]);
    }
#pragma unroll
    for (int n = 0; n < NF; ++n) {
      int c = wc * (NF * 16) + n * 16 + lr;
      bfh[n] = *reinterpret_cast<const bf16x8*>(&Bh[c * SK + kg * 8]);
      bfl[n] = *reinterpret_cast<const bf16x8*>(&Bl[c * SK + kg * 8]);
    }
#pragma unroll
    for (int m = 0; m < 4; ++m)
#pragma unroll
      for (int n = 0; n < NF; ++n) {
        acc[m][n] = __builtin_amdgcn_mfma_f32_16x16x32_bf16(afh[m], bfh[n], acc[m][n], 0, 0, 0);
        acc[m][n] = __builtin_amdgcn_mfma_f32_16x16x32_bf16(afl[m], bfh[n], acc[m][n], 0, 0, 0);
        acc[m][n] = __builtin_amdgcn_mfma_f32_16x16x32_bf16(afh[m], bfl[n], acc[m][n], 0, 0, 0);
      }
    __syncthreads();
  }

  // epilogue: C/D layout col = lane&15, row = (lane>>4)*4 + reg
#pragma unroll
  for (int m = 0; m < 4; ++m) {
#pragma unroll
    for (int n = 0; n < NF; ++n) {
      int gc = wc * (NF * 16) + n * 16 + lr;
#pragma unroll
      for (int q = 0; q < 4; ++q) {
        int gr = row0 + wr * 64 + m * 16 + kg * 4 + q;
        if (gr < M) {
          float v = acc[m][n][q];
          if (EPI == 0) {
            v = fmaxf(v + bias[gc], 0.f);
            C16u[(size_t)gr * BN + gc] = __float2half(v);
            C16s[(size_t)gr * BN + gc] = __float2half(v * dinv[gr]);
          } else if (EPI == 1) {
            v = fmaxf(fmaf(p0, A[(size_t)gr * K + gc], p1 * v), 0.f);
            C16s[(size_t)gr * BN + gc] = __float2half(v * dinv[gr]);
          } else if (EPI == 3) {
            v = fmaxf(fmaf(p0, A[(size_t)gr * K + gc], p1 * v), 0.f);
            C[(size_t)gr * BN + gc] = v;
          } else {
            C[(size_t)gr * BN + gc] = v + bias[gc];
          }
        }
      }
    }
  }
}

// ---------------- launch ----------------

extern "C" void kernel_launch(void* const* d_in, const int* in_sizes, int n_in,
                              void* d_out, int out_size, void* d_ws, size_t ws_size,
                              hipStream_t stream) {
  const float* x     = (const float*)d_in[0];
  const int*   ei    = (const int*)d_in[1];
  const float* W_in  = (const float*)d_in[2];
  const float* b_in  = (const float*)d_in[3];
  const float* W_cv  = (const float*)d_in[4];
  const float* W_out = (const float*)d_in[5];
  const float* b_out = (const float*)d_in[6];
  float* out = (float*)d_out;

  char* ws = (char*)d_ws;
  size_t off = 0;
  auto alloc = [&](size_t bytes) {
    char* p = ws + off;
    off = (off + bytes + 255) & ~(size_t)255;
    return p;
  };
  int*    deg     = (int*)alloc((size_t)NN * 4);
  int*    row_ptr = (int*)alloc((size_t)NN * 4);
  int*    cursor  = (int*)alloc((size_t)NN * 4);
  int*    bsum    = (int*)alloc(512 * 4);
  float*  dinv    = (float*)alloc((size_t)NN * 4);
  int*    col     = (int*)alloc((size_t)(EE + NN) * 4);
  __half* h016u   = (__half*)alloc((size_t)NN * HIDC * 2);
  __half* h016s   = (__half*)alloc((size_t)NN * HIDC * 2);
  __half* hsA     = (__half*)alloc((size_t)NN * HIDC * 2);
  __half* hsB     = (__half*)alloc((size_t)NN * HIDC * 2);
  float*  zb      = (float*)alloc((size_t)NN * HIDC * 4);
  float*  hb      = (float*)alloc((size_t)NN * HIDC * 4);
  unsigned short* win_h  = (unsigned short*)alloc((size_t)HIDC * 512 * 2);
  unsigned short* win_l  = (unsigned short*)alloc((size_t)HIDC * 512 * 2);
  unsigned short* wcv_h  = (unsigned short*)alloc((size_t)NLAYER * HIDC * HIDC * 2);
  unsigned short* wcv_l  = (unsigned short*)alloc((size_t)NLAYER * HIDC * HIDC * 2);
  unsigned short* wout_h = (unsigned short*)alloc((size_t)OUTC * HIDC * 2);
  unsigned short* wout_l = (unsigned short*)alloc((size_t)OUTC * HIDC * 2);

  const int* srcp = ei;
  const int* dstp = ei + EE;

  hipMemsetAsync(deg, 0, (size_t)NN * 4, stream);
  k_count_deg<<<(EE + 255) / 256, 256, 0, stream>>>(dstp, deg, EE);
  int nb = (NN + 255) / 256;  // 391 <= 512
  k_scan_block_sums<<<nb, 256, 0, stream>>>(deg, bsum, NN);
  k_scan_partials<<<1, 512, 0, stream>>>(bsum, nb);
  k_scan_final<<<nb, 256, 0, stream>>>(deg, bsum, row_ptr, NN);
  k_init_rows<<<(NN + 255) / 256, 256, 0, stream>>>(deg, row_ptr, cursor, col, dinv, NN);
  k_fill_edges<<<(EE + 255) / 256, 256, 0, stream>>>(srcp, dstp, cursor, col, EE);

  // pre-split weights into transposed hi/lo bf16
  k_prep_w<<<(HIDC * 512 + 255) / 256, 256, 0, stream>>>(W_in, win_h, win_l, INC, HIDC, 512);
  for (int l = 0; l < NLAYER; ++l)
    k_prep_w<<<(HIDC * HIDC + 255) / 256, 256, 0, stream>>>(
        W_cv + (size_t)l * HIDC * HIDC, wcv_h + (size_t)l * HIDC * HIDC,
        wcv_l + (size_t)l * HIDC * HIDC, HIDC, HIDC, HIDC);
  k_prep_w<<<(OUTC * HIDC + 255) / 256, 256, 0, stream>>>(W_out, wout_h, wout_l, HIDC, OUTC, HIDC);

  int gblk = (NN + 127) / 128;
  // h0 = relu(x @ W_in + b_in) -> fp16 unscaled + scaled
  k_mgemm<128, 0><<<gblk, 256, 0, stream>>>(x, win_h, win_l, b_in, nullptr, h016u, h016s,
                                            dinv, NN, INC, 512, 0.f, 0.f);

  const __half* hcur = h016s;
  for (int l = 0; l < NLAYER; ++l) {
    k_agg<<<((size_t)NN * 64 + 255) / 256, 256, 0, stream>>>(hcur, h016u, zb, row_ptr, deg, col, dinv);
    float beta = logf(0.5f / (float)(l + 1) + 1.0f);
    const unsigned short* wh = wcv_h + (size_t)l * HIDC * HIDC;
    const unsigned short* wl = wcv_l + (size_t)l * HIDC * HIDC;
    if (l < NLAYER - 1) {
      __half* tgt = (l & 1) ? hsB : hsA;
      k_mgemm<128, 1><<<gblk, 256, 0, stream>>>(zb, wh, wl, nullptr, nullptr, nullptr, tgt,
                                                dinv, NN, HIDC, HIDC, 1.0f - beta, beta);
      hcur = tgt;
    } else {
      k_mgemm<128, 3><<<gblk, 256, 0, stream>>>(zb, wh, wl, nullptr, hb, nullptr, nullptr,
                                                dinv, NN, HIDC, HIDC, 1.0f - beta, beta);
    }
  }
  // out = h @ W_out + b_out
  k_mgemm<64, 2><<<gblk, 256, 0, stream>>>(hb, wout_h, wout_l, b_out, out, nullptr, nullptr,
                                           dinv, NN, HIDC, HIDC, 0.f, 0.f);
}

// Round 6
// 1261.570 us; speedup vs baseline: 2.2308x; 1.1198x over previous
//
#include <hip/hip_runtime.h>
#include <hip/hip_fp16.h>
#include <cmath>

#define NN 100000
#define EE 1600000
#define INC 500
#define HIDC 128
#define OUTC 64
#define NLAYER 8
#define NCH16 6250          // ceil(NN/16)
#define NCH16_PAD 6252      // padded to multiple of 4 (64-row GEMM chunks)
#define NCH64 1563          // ceil(NN/64)

typedef float f32x4 __attribute__((ext_vector_type(4)));
typedef __bf16 bf16x8 __attribute__((ext_vector_type(8)));
typedef short s16x4 __attribute__((ext_vector_type(4)));
typedef short s16x8 __attribute__((ext_vector_type(8)));

__device__ __forceinline__ unsigned short f2bf_rn(float f) {
  unsigned u = __float_as_uint(f);
  unsigned r = u + 0x7fffu + ((u >> 16) & 1u);
  return (unsigned short)(r >> 16);
}
__device__ __forceinline__ float bf2f(unsigned short h) {
  return __uint_as_float(((unsigned)h) << 16);
}

// frag layout addr for (row, k), K pitch Kp: [(row/16)][k/8][row%16][k%8]
__device__ __forceinline__ int fraddr(int row, int k, int Kp) {
  return (row >> 4) * (Kp * 16) + (k >> 3) * 128 + (row & 15) * 8 + (k & 7);
}

// ---------------- graph preprocessing ----------------

__global__ void k_count_deg(const int* __restrict__ dst, int* __restrict__ deg, int E) {
  int e = blockIdx.x * blockDim.x + threadIdx.x;
  if (e < E) atomicAdd(&deg[dst[e]], 1);
}

__global__ void k_scan_block_sums(const int* __restrict__ deg, int* __restrict__ bsum, int n) {
  __shared__ int sm[256];
  int i = blockIdx.x * 256 + threadIdx.x;
  int v = (i < n) ? deg[i] + 1 : 0;  // +1 for self-loop
  sm[threadIdx.x] = v;
  __syncthreads();
  for (int s = 128; s > 0; s >>= 1) {
    if (threadIdx.x < s) sm[threadIdx.x] += sm[threadIdx.x + s];
    __syncthreads();
  }
  if (threadIdx.x == 0) bsum[blockIdx.x] = sm[0];
}

__global__ void k_scan_partials(int* __restrict__ bsum, int nb) {
  __shared__ int sm[512];
  int t = threadIdx.x;
  sm[t] = (t < nb) ? bsum[t] : 0;
  __syncthreads();
  for (int s = 1; s < 512; s <<= 1) {
    int v = (t >= s) ? sm[t - s] : 0;
    __syncthreads();
    sm[t] += v;
    __syncthreads();
  }
  if (t < nb) bsum[t] = (t == 0) ? 0 : sm[t - 1];  // exclusive
}

__global__ void k_scan_final(const int* __restrict__ deg, const int* __restrict__ bsum,
                             int* __restrict__ row_ptr, int n) {
  __shared__ int sm[256];
  int i = blockIdx.x * 256 + threadIdx.x;
  int v = (i < n) ? deg[i] + 1 : 0;
  sm[threadIdx.x] = v;
  __syncthreads();
  for (int s = 1; s < 256; s <<= 1) {
    int u = (threadIdx.x >= s) ? sm[threadIdx.x - s] : 0;
    __syncthreads();
    sm[threadIdx.x] += u;
    __syncthreads();
  }
  if (i < n) row_ptr[i] = bsum[blockIdx.x] + sm[threadIdx.x] - v;  // exclusive
}

__global__ void k_init_rows(const int* __restrict__ deg, const int* __restrict__ row_ptr,
                            int* __restrict__ cursor, int* __restrict__ col,
                            float* __restrict__ dinv, int n) {
  int i = blockIdx.x * blockDim.x + threadIdx.x;
  if (i < n) {
    int rp = row_ptr[i];
    col[rp] = i;          // self-loop entry first (deterministic)
    cursor[i] = rp + 1;
    dinv[i] = rsqrtf((float)(deg[i] + 1));
  }
}

__global__ void k_fill_edges(const int* __restrict__ src, const int* __restrict__ dst,
                             int* __restrict__ cursor, int* __restrict__ col, int E) {
  int e = blockIdx.x * blockDim.x + threadIdx.x;
  if (e < E) {
    int pos = atomicAdd(&cursor[dst[e]], 1);
    col[pos] = src[e];
  }
}

// ---- W_in pre-split (row-major transposed [N][Kp]) for the staged input GEMM ----

__global__ void k_prep_w(const float* __restrict__ W, unsigned short* __restrict__ hi,
                         unsigned short* __restrict__ lo, int K, int N, int Kp) {
  int i = blockIdx.x * 256 + threadIdx.x;
  if (i >= N * Kp) return;
  int n = i / Kp, k = i % Kp;
  float v = (k < K) ? W[(size_t)k * N + n] : 0.f;
  unsigned short h = f2bf_rn(v);
  unsigned short l = f2bf_rn(v - bf2f(h));
  hi[i] = h;
  lo[i] = l;
}

// ---- W pre-split into FRAGMENT layout, optional identity fold: M = idc*I + ws*W ----

__global__ void k_prep_wf(const float* __restrict__ W, unsigned short* __restrict__ fh,
                          unsigned short* __restrict__ fl, int K, int N,
                          float idc, float ws) {
  int i = blockIdx.x * 256 + threadIdx.x;
  if (i >= N * K) return;
  int n = i / K, k = i % K;
  float v = ws * W[(size_t)k * N + n] + ((k == n) ? idc : 0.f);
  unsigned short h = f2bf_rn(v);
  unsigned short l = f2bf_rn(v - bf2f(h));
  int a = fraddr(n, k, K);
  fh[a] = h;
  fl[a] = l;
}

// ---------------- aggregation: z = 0.9*dinv_dst*sum(h'_src) + 0.1*h0 ----------------
// h' = dinv*h pre-scaled fp16. One wave per dst node. 4 lane-groups of 16;
// group g handles edge chunk slot g, lane loads 16B (8 fp16 features).
// Output: z as hi/lo bf16 in MFMA fragment layout (zfh / zfl).

__global__ void __launch_bounds__(256) k_agg(
    const __half* __restrict__ hs, const __half* __restrict__ h0u,
    unsigned short* __restrict__ zfh, unsigned short* __restrict__ zfl,
    const int* __restrict__ row_ptr, const int* __restrict__ deg,
    const int* __restrict__ col, const float* __restrict__ dinv) {
  int wid = (blockIdx.x * blockDim.x + threadIdx.x) >> 6;
  int lane = threadIdx.x & 63;
  if (wid >= NN) return;
  int g = lane >> 4;    // edge slot within chunk
  int fl = lane & 15;   // feature sub-lane: features [8*fl, 8*fl+8)
  int start = row_ptr[wid];
  int cnt = deg[wid] + 1;
  int nch = (cnt + 3) >> 2;

  float acc[8];
#pragma unroll
  for (int j = 0; j < 8; ++j) acc[j] = 0.f;

  auto load_chunk = [&](int ch, s16x8& v, float& m) {
    int e = ch * 4 + g;
    bool valid = e < cnt;
    int c = col[start + (valid ? e : 0)];
    m = valid ? 1.f : 0.f;
    v = *reinterpret_cast<const s16x8*>(&hs[(size_t)c * HIDC + fl * 8]);
  };

  s16x8 curv; float curm;
  load_chunk(0, curv, curm);
  for (int ch = 0; ch < nch; ++ch) {
    s16x8 nv = {}; float nm = 0.f;
    if (ch + 1 < nch) load_chunk(ch + 1, nv, nm);
    const __half2* hp = reinterpret_cast<const __half2*>(&curv);
#pragma unroll
    for (int j = 0; j < 4; ++j) {
      float2 f = __half22float2(hp[j]);
      acc[2 * j]     = fmaf(curm, f.x, acc[2 * j]);
      acc[2 * j + 1] = fmaf(curm, f.y, acc[2 * j + 1]);
    }
    curv = nv; curm = nm;
  }

  // combine the 4 group-partials: butterfly over lane bits 4..5 (all lanes get sum)
#pragma unroll
  for (int j = 0; j < 8; ++j) {
    acc[j] += __shfl_xor(acc[j], 16, 64);
    acc[j] += __shfl_xor(acc[j], 32, 64);
  }

  if (g < 2) {
    float dr = dinv[wid] * 0.9f;
    s16x8 r0 = *reinterpret_cast<const s16x8*>(&h0u[(size_t)wid * HIDC + fl * 8]);
    const __half2* r0p = reinterpret_cast<const __half2*>(&r0);
    float o[8];
#pragma unroll
    for (int j = 0; j < 4; ++j) {
      float2 f0 = __half22float2(r0p[j]);
      o[2 * j]     = fmaf(dr, acc[2 * j],     0.1f * f0.x);
      o[2 * j + 1] = fmaf(dr, acc[2 * j + 1], 0.1f * f0.y);
    }
    int base = (wid >> 4) * (HIDC * 16) + fl * 128 + (wid & 15) * 8;
    s16x8 w;
    if (g == 0) {
#pragma unroll
      for (int j = 0; j < 8; ++j) w[j] = (short)f2bf_rn(o[j]);
      *reinterpret_cast<s16x8*>(&zfh[base]) = w;
    } else {
#pragma unroll
      for (int j = 0; j < 8; ++j) {
        unsigned short h = f2bf_rn(o[j]);
        w[j] = (short)f2bf_rn(o[j] - bf2f(h));
      }
      *reinterpret_cast<s16x8*>(&zfl[base]) = w;
    }
  }
}

// ---------------- fragment GEMM: C = epi(A @ B), A/B pre-split frag-layout bf16 ----------------
// K = 128. One wave per 64-row chunk, B (hi/lo) LDS-resident, A direct from global.
// EPI 0: relu -> fp16 scaled row-major (mid layer, feeds next agg)
// EPI 1: relu -> hi/lo bf16 frag layout (last layer, feeds out GEMM)
// EPI 2: + bias -> fp32 row-major (output projection)

template <int NOUT, int EPI>
__global__ void __launch_bounds__(256) k_fgemm(
    const unsigned short* __restrict__ Afh, const unsigned short* __restrict__ Afl,
    const unsigned short* __restrict__ Bfh, const unsigned short* __restrict__ Bfl,
    const float* __restrict__ bias, const float* __restrict__ dinv,
    __half* __restrict__ Cs, unsigned short* __restrict__ Cfh,
    unsigned short* __restrict__ Cfl, float* __restrict__ Cf, int M) {
  constexpr int KP = 128;
  constexpr int NF = NOUT / 16;
  __shared__ __align__(16) unsigned short Bh[NOUT * KP];
  __shared__ __align__(16) unsigned short Bl[NOUT * KP];
  for (int i = threadIdx.x * 8; i < NOUT * KP; i += 256 * 8) {
    *reinterpret_cast<s16x8*>(&Bh[i]) = *reinterpret_cast<const s16x8*>(&Bfh[i]);
    *reinterpret_cast<s16x8*>(&Bl[i]) = *reinterpret_cast<const s16x8*>(&Bfl[i]);
  }
  __syncthreads();

  int wv = threadIdx.x >> 6, lane = threadIdx.x & 63;
  int lr = lane & 15, kg = lane >> 4;
  int cid = blockIdx.x * 4 + wv;  // 64-row chunk
  if (cid >= NCH64) return;
  int row0 = cid * 64;

  f32x4 acc[4][NF];
#pragma unroll
  for (int m = 0; m < 4; ++m)
#pragma unroll
    for (int n = 0; n < NF; ++n) acc[m][n] = {0.f, 0.f, 0.f, 0.f};

  const int abase = (row0 >> 4) * (KP * 16) + kg * 128 + lr * 8;
  const unsigned short* Ahp = Afh + abase;
  const unsigned short* Alp = Afl + abase;

  bf16x8 ah[4], al[4];
#pragma unroll
  for (int m = 0; m < 4; ++m) {
    ah[m] = *reinterpret_cast<const bf16x8*>(Ahp + m * 2048);
    al[m] = *reinterpret_cast<const bf16x8*>(Alp + m * 2048);
  }
#pragma unroll
  for (int kt = 0; kt < 4; ++kt) {
    bf16x8 nah[4], nal[4];
    if (kt < 3) {
#pragma unroll
      for (int m = 0; m < 4; ++m) {
        nah[m] = *reinterpret_cast<const bf16x8*>(Ahp + m * 2048 + (kt + 1) * 512);
        nal[m] = *reinterpret_cast<const bf16x8*>(Alp + m * 2048 + (kt + 1) * 512);
      }
    }
#pragma unroll
    for (int n = 0; n < NF; ++n) {
      int bb = n * 2048 + kt * 512 + kg * 128 + lr * 8;
      bf16x8 bh = *reinterpret_cast<const bf16x8*>(&Bh[bb]);
      bf16x8 bl = *reinterpret_cast<const bf16x8*>(&Bl[bb]);
#pragma unroll
      for (int m = 0; m < 4; ++m) {
        acc[m][n] = __builtin_amdgcn_mfma_f32_16x16x32_bf16(ah[m], bh, acc[m][n], 0, 0, 0);
        acc[m][n] = __builtin_amdgcn_mfma_f32_16x16x32_bf16(al[m], bh, acc[m][n], 0, 0, 0);
        acc[m][n] = __builtin_amdgcn_mfma_f32_16x16x32_bf16(ah[m], bl, acc[m][n], 0, 0, 0);
      }
    }
    if (kt < 3) {
#pragma unroll
      for (int m = 0; m < 4; ++m) { ah[m] = nah[m]; al[m] = nal[m]; }
    }
  }

  // epilogue: C(row = m*16 + kg*4 + q, col = n*16 + lr)
#pragma unroll
  for (int m = 0; m < 4; ++m) {
#pragma unroll
    for (int q = 0; q < 4; ++q) {
      int gr = row0 + m * 16 + kg * 4 + q;
      if (gr >= M) continue;
      float dv = (EPI == 0) ? dinv[gr] : 0.f;
#pragma unroll
      for (int n = 0; n < NF; ++n) {
        int gc = n * 16 + lr;
        float v = acc[m][n][q];
        if (EPI == 0) {
          v = fmaxf(v, 0.f);
          Cs[(size_t)gr * NOUT + gc] = __float2half(v * dv);
        } else if (EPI == 1) {
          v = fmaxf(v, 0.f);
          unsigned short h = f2bf_rn(v);
          int a = fraddr(gr, gc, KP);
          Cfh[a] = h;
          Cfl[a] = f2bf_rn(v - bf2f(h));
        } else {
          Cf[(size_t)gr * NOUT + gc] = v + bias[gc];
        }
      }
    }
  }
}

// ---------------- staged MFMA bf16x3 GEMM for the input projection ----------------
// h0 = relu(x @ W_in + b_in) -> fp16 unscaled + fp16 scaled

__global__ void __launch_bounds__(256) k_mgemm_in(
    const float* __restrict__ A, const unsigned short* __restrict__ Bhg,
    const unsigned short* __restrict__ Blg, const float* __restrict__ bias,
    __half* __restrict__ C16u, __half* __restrict__ C16s,
    const float* __restrict__ dinv, int M, int K, int Kp) {
  constexpr int BN = 128;
  constexpr int SK = 40;
  constexpr int NF = 4;
  __shared__ __align__(16) unsigned short Ah[128 * SK];
  __shared__ __align__(16) unsigned short Al[128 * SK];
  __shared__ __align__(16) unsigned short Bh[BN * SK];
  __shared__ __align__(16) unsigned short Bl[BN * SK];
  int tid = threadIdx.x;
  int wid = tid >> 6, lane = tid & 63;
  int wr = wid >> 1, wc = wid & 1;
  int lr = lane & 15, kg = lane >> 4;
  int row0 = blockIdx.x * 128;

  f32x4 acc[4][NF];
#pragma unroll
  for (int m = 0; m < 4; ++m)
#pragma unroll
    for (int n = 0; n < NF; ++n) acc[m][n] = {0.f, 0.f, 0.f, 0.f};

  for (int kt = 0; kt < Kp; kt += 32) {
#pragma unroll
    for (int p = 0; p < 4; ++p) {
      int idx = tid + p * 256;
      int r = idx >> 3, kq = idx & 7;
      int gr = row0 + r, gk = kt + kq * 4;
      float4 v = make_float4(0.f, 0.f, 0.f, 0.f);
      if (gr < M && gk < K) v = *reinterpret_cast<const float4*>(&A[(size_t)gr * K + gk]);
      const float* vp = &v.x;
      s16x4 h4, l4;
#pragma unroll
      for (int e = 0; e < 4; ++e) {
        unsigned short h = f2bf_rn(vp[e]);
        h4[e] = (short)h;
        l4[e] = (short)f2bf_rn(vp[e] - bf2f(h));
      }
      *reinterpret_cast<s16x4*>(&Ah[r * SK + kq * 4]) = h4;
      *reinterpret_cast<s16x4*>(&Al[r * SK + kq * 4]) = l4;
    }
#pragma unroll
    for (int p = 0; p < 2; ++p) {
      int idx = tid + p * 256;
      int n = idx >> 2, kq8 = idx & 3;
      size_t so = (size_t)n * Kp + kt + kq8 * 8;
      *reinterpret_cast<s16x8*>(&Bh[n * SK + kq8 * 8]) =
          *reinterpret_cast<const s16x8*>(&Bhg[so]);
      *reinterpret_cast<s16x8*>(&Bl[n * SK + kq8 * 8]) =
          *reinterpret_cast<const s16x8*>(&Blg[so]);
    }
    __syncthreads();

    bf16x8 afh[4], afl[4], bfh[NF], bfl[NF];
#pragma unroll
    for (int m = 0; m < 4; ++m) {
      int r = wr * 64 + m * 16 + lr;
      afh[m] = *reinterpret_cast<const bf16x8*>(&Ah[r * SK + kg * 8]);
      afl[m] = *reinterpret_cast<const bf16x8*>(&Al[r * SK + kg * 8]);
    }
#pragma unroll
    for (int n = 0; n < NF; ++n) {
      int c = wc * 64 + n * 16 + lr;
      bfh[n] = *reinterpret_cast<const bf16x8*>(&Bh[c * SK + kg * 8]);
      bfl[n] = *reinterpret_cast<const bf16x8*>(&Bl[c * SK + kg * 8]);
    }
#pragma unroll
    for (int m = 0; m < 4; ++m)
#pragma unroll
      for (int n = 0; n < NF; ++n) {
        acc[m][n] = __builtin_amdgcn_mfma_f32_16x16x32_bf16(afh[m], bfh[n], acc[m][n], 0, 0, 0);
        acc[m][n] = __builtin_amdgcn_mfma_f32_16x16x32_bf16(afl[m], bfh[n], acc[m][n], 0, 0, 0);
        acc[m][n] = __builtin_amdgcn_mfma_f32_16x16x32_bf16(afh[m], bfl[n], acc[m][n], 0, 0, 0);
      }
    __syncthreads();
  }

#pragma unroll
  for (int m = 0; m < 4; ++m) {
#pragma unroll
    for (int n = 0; n < NF; ++n) {
      int gc = wc * 64 + n * 16 + lr;
#pragma unroll
      for (int q = 0; q < 4; ++q) {
        int gr = row0 + wr * 64 + m * 16 + kg * 4 + q;
        if (gr < M) {
          float v = fmaxf(acc[m][n][q] + bias[gc], 0.f);
          C16u[(size_t)gr * BN + gc] = __float2half(v);
          C16s[(size_t)gr * BN + gc] = __float2half(v * dinv[gr]);
        }
      }
    }
  }
}

// ---------------- launch ----------------

extern "C" void kernel_launch(void* const* d_in, const int* in_sizes, int n_in,
                              void* d_out, int out_size, void* d_ws, size_t ws_size,
                              hipStream_t stream) {
  const float* x     = (const float*)d_in[0];
  const int*   ei    = (const int*)d_in[1];
  const float* W_in  = (const float*)d_in[2];
  const float* b_in  = (const float*)d_in[3];
  const float* W_cv  = (const float*)d_in[4];
  const float* W_out = (const float*)d_in[5];
  const float* b_out = (const float*)d_in[6];
  float* out = (float*)d_out;

  char* ws = (char*)d_ws;
  size_t off = 0;
  auto alloc = [&](size_t bytes) {
    char* p = ws + off;
    off = (off + bytes + 255) & ~(size_t)255;
    return p;
  };
  int*    deg     = (int*)alloc((size_t)NN * 4);
  int*    row_ptr = (int*)alloc((size_t)NN * 4);
  int*    cursor  = (int*)alloc((size_t)NN * 4);
  int*    bsum    = (int*)alloc(512 * 4);
  float*  dinv    = (float*)alloc((size_t)NN * 4);
  int*    col     = (int*)alloc((size_t)(EE + NN) * 4);
  __half* h016u   = (__half*)alloc((size_t)NN * HIDC * 2);
  __half* h016s   = (__half*)alloc((size_t)NN * HIDC * 2);
  __half* hsA     = (__half*)alloc((size_t)NN * HIDC * 2);
  __half* hsB     = (__half*)alloc((size_t)NN * HIDC * 2);
  size_t fragsz = (size_t)NCH16_PAD * HIDC * 16;  // elements
  unsigned short* zfh = (unsigned short*)alloc(fragsz * 2);
  unsigned short* zfl = (unsigned short*)alloc(fragsz * 2);
  unsigned short* hfh = (unsigned short*)alloc(fragsz * 2);
  unsigned short* hfl = (unsigned short*)alloc(fragsz * 2);
  unsigned short* win_h  = (unsigned short*)alloc((size_t)HIDC * 512 * 2);
  unsigned short* win_l  = (unsigned short*)alloc((size_t)HIDC * 512 * 2);
  unsigned short* wcv_h  = (unsigned short*)alloc((size_t)NLAYER * HIDC * HIDC * 2);
  unsigned short* wcv_l  = (unsigned short*)alloc((size_t)NLAYER * HIDC * HIDC * 2);
  unsigned short* wout_h = (unsigned short*)alloc((size_t)OUTC * HIDC * 2);
  unsigned short* wout_l = (unsigned short*)alloc((size_t)OUTC * HIDC * 2);

  const int* srcp = ei;
  const int* dstp = ei + EE;

  hipMemsetAsync(deg, 0, (size_t)NN * 4, stream);
  // zero the pad chunks (rows NN..NCH16_PAD*16) of the frag arrays
  size_t padoff = (size_t)NCH16 * HIDC * 16;
  size_t padlen = ((size_t)(NCH16_PAD - NCH16) * HIDC * 16) * 2;
  hipMemsetAsync(zfh + padoff, 0, padlen, stream);
  hipMemsetAsync(zfl + padoff, 0, padlen, stream);
  hipMemsetAsync(hfh + padoff, 0, padlen, stream);
  hipMemsetAsync(hfl + padoff, 0, padlen, stream);

  k_count_deg<<<(EE + 255) / 256, 256, 0, stream>>>(dstp, deg, EE);
  int nb = (NN + 255) / 256;  // 391 <= 512
  k_scan_block_sums<<<nb, 256, 0, stream>>>(deg, bsum, NN);
  k_scan_partials<<<1, 512, 0, stream>>>(bsum, nb);
  k_scan_final<<<nb, 256, 0, stream>>>(deg, bsum, row_ptr, NN);
  k_init_rows<<<(NN + 255) / 256, 256, 0, stream>>>(deg, row_ptr, cursor, col, dinv, NN);
  k_fill_edges<<<(EE + 255) / 256, 256, 0, stream>>>(srcp, dstp, cursor, col, EE);

  // weight prep
  k_prep_w<<<(HIDC * 512 + 255) / 256, 256, 0, stream>>>(W_in, win_h, win_l, INC, HIDC, 512);
  for (int l = 0; l < NLAYER; ++l) {
    float beta = logf(0.5f / (float)(l + 1) + 1.0f);
    k_prep_wf<<<(HIDC * HIDC + 255) / 256, 256, 0, stream>>>(
        W_cv + (size_t)l * HIDC * HIDC, wcv_h + (size_t)l * HIDC * HIDC,
        wcv_l + (size_t)l * HIDC * HIDC, HIDC, HIDC, 1.0f - beta, beta);
  }
  k_prep_wf<<<(OUTC * HIDC + 255) / 256, 256, 0, stream>>>(W_out, wout_h, wout_l, HIDC, OUTC,
                                                           0.f, 1.f);

  // h0 = relu(x @ W_in + b_in) -> fp16 unscaled + scaled
  k_mgemm_in<<<(NN + 127) / 128, 256, 0, stream>>>(x, win_h, win_l, b_in, h016u, h016s,
                                                   dinv, NN, INC, 512);

  int fgrid = (NCH64 + 3) / 4;
  const __half* hcur = h016s;
  for (int l = 0; l < NLAYER; ++l) {
    k_agg<<<((size_t)NN * 64 + 255) / 256, 256, 0, stream>>>(hcur, h016u, zfh, zfl,
                                                             row_ptr, deg, col, dinv);
    const unsigned short* wh = wcv_h + (size_t)l * HIDC * HIDC;
    const unsigned short* wl = wcv_l + (size_t)l * HIDC * HIDC;
    if (l < NLAYER - 1) {
      __half* tgt = (l & 1) ? hsB : hsA;
      k_fgemm<128, 0><<<fgrid, 256, 0, stream>>>(zfh, zfl, wh, wl, nullptr, dinv,
                                                 tgt, nullptr, nullptr, nullptr, NN);
      hcur = tgt;
    } else {
      k_fgemm<128, 1><<<fgrid, 256, 0, stream>>>(zfh, zfl, wh, wl, nullptr, nullptr,
                                                 nullptr, hfh, hfl, nullptr, NN);
    }
  }
  // out = h @ W_out + b_out
  k_fgemm<64, 2><<<fgrid, 256, 0, stream>>>(hfh, hfl, wout_h, wout_l, b_out, nullptr,
                                            nullptr, nullptr, nullptr, out, NN);
}

// Round 7
// 1149.291 us; speedup vs baseline: 2.4487x; 1.0977x over previous
//
#include <hip/hip_runtime.h>
#include <hip/hip_fp16.h>
#include <cmath>

#define NN 100000
#define EE 1600000
#define INC 500
#define HIDC 128
#define OUTC 64
#define NLAYER 8
#define NW32 3125           // NN / 32 exactly

typedef float f32x4 __attribute__((ext_vector_type(4)));
typedef __bf16 bf16x8 __attribute__((ext_vector_type(8)));
typedef _Float16 f16x8 __attribute__((ext_vector_type(8)));
typedef short s16x4 __attribute__((ext_vector_type(4)));
typedef short s16x8 __attribute__((ext_vector_type(8)));

__device__ __forceinline__ unsigned short f2bf_rn(float f) {
  unsigned u = __float_as_uint(f);
  unsigned r = u + 0x7fffu + ((u >> 16) & 1u);
  return (unsigned short)(r >> 16);
}
__device__ __forceinline__ float bf2f(unsigned short h) {
  return __uint_as_float(((unsigned)h) << 16);
}

// frag layout addr for (row, k), K pitch Kp: [(row/16)][k/8][row%16][k%8]
__device__ __forceinline__ int fraddr(int row, int k, int Kp) {
  return (row >> 4) * (Kp * 16) + (k >> 3) * 128 + (row & 15) * 8 + (k & 7);
}

// ---------------- graph preprocessing ----------------

__global__ void k_count_deg(const int* __restrict__ dst, int* __restrict__ deg, int E) {
  int e = blockIdx.x * blockDim.x + threadIdx.x;
  if (e < E) atomicAdd(&deg[dst[e]], 1);
}

__global__ void k_scan_block_sums(const int* __restrict__ deg, int* __restrict__ bsum, int n) {
  __shared__ int sm[256];
  int i = blockIdx.x * 256 + threadIdx.x;
  int v = (i < n) ? deg[i] + 1 : 0;  // +1 for self-loop
  sm[threadIdx.x] = v;
  __syncthreads();
  for (int s = 128; s > 0; s >>= 1) {
    if (threadIdx.x < s) sm[threadIdx.x] += sm[threadIdx.x + s];
    __syncthreads();
  }
  if (threadIdx.x == 0) bsum[blockIdx.x] = sm[0];
}

__global__ void k_scan_partials(int* __restrict__ bsum, int nb) {
  __shared__ int sm[512];
  int t = threadIdx.x;
  sm[t] = (t < nb) ? bsum[t] : 0;
  __syncthreads();
  for (int s = 1; s < 512; s <<= 1) {
    int v = (t >= s) ? sm[t - s] : 0;
    __syncthreads();
    sm[t] += v;
    __syncthreads();
  }
  if (t < nb) bsum[t] = (t == 0) ? 0 : sm[t - 1];  // exclusive
}

__global__ void k_scan_final(const int* __restrict__ deg, const int* __restrict__ bsum,
                             int* __restrict__ row_ptr, int n) {
  __shared__ int sm[256];
  int i = blockIdx.x * 256 + threadIdx.x;
  int v = (i < n) ? deg[i] + 1 : 0;
  sm[threadIdx.x] = v;
  __syncthreads();
  for (int s = 1; s < 256; s <<= 1) {
    int u = (threadIdx.x >= s) ? sm[threadIdx.x - s] : 0;
    __syncthreads();
    sm[threadIdx.x] += u;
    __syncthreads();
  }
  if (i < n) row_ptr[i] = bsum[blockIdx.x] + sm[threadIdx.x] - v;  // exclusive
}

__global__ void k_init_rows(const int* __restrict__ deg, const int* __restrict__ row_ptr,
                            int* __restrict__ cursor, int* __restrict__ col,
                            float* __restrict__ dinv, int n) {
  int i = blockIdx.x * blockDim.x + threadIdx.x;
  if (i < n) {
    int rp = row_ptr[i];
    col[rp] = i;          // self-loop entry first (deterministic)
    cursor[i] = rp + 1;
    dinv[i] = rsqrtf((float)(deg[i] + 1));
  }
}

__global__ void k_fill_edges(const int* __restrict__ src, const int* __restrict__ dst,
                             int* __restrict__ cursor, int* __restrict__ col, int E) {
  int e = blockIdx.x * blockDim.x + threadIdx.x;
  if (e < E) {
    int pos = atomicAdd(&cursor[dst[e]], 1);
    col[pos] = src[e];
  }
}

// ---- W_in pre-split (row-major transposed [N][Kp]) for the staged input GEMM ----

__global__ void k_prep_w(const float* __restrict__ W, unsigned short* __restrict__ hi,
                         unsigned short* __restrict__ lo, int K, int N, int Kp) {
  int i = blockIdx.x * 256 + threadIdx.x;
  if (i >= N * Kp) return;
  int n = i / Kp, k = i % Kp;
  float v = (k < K) ? W[(size_t)k * N + n] : 0.f;
  unsigned short h = f2bf_rn(v);
  unsigned short l = f2bf_rn(v - bf2f(h));
  hi[i] = h;
  lo[i] = l;
}

// ---- W -> fp16 fragment layout, optional identity fold: M = idc*I + ws*W ----

__global__ void k_prep_wf16(const float* __restrict__ W, __half* __restrict__ f,
                            int K, int N, float idc, float ws) {
  int i = blockIdx.x * 256 + threadIdx.x;
  if (i >= N * K) return;
  int n = i / K, k = i % K;
  float v = ws * W[(size_t)k * N + n] + ((k == n) ? idc : 0.f);
  f[fraddr(n, k, K)] = __float2half(v);
}

// ---------------- aggregation: z = 0.9*dinv_dst*sum(h'_src) + 0.1*h0 ----------------
// h' = dinv*h pre-scaled fp16. One wave per dst node. 4 lane-groups of 16;
// group g handles edge chunk slot g, lane loads 16B (8 fp16 features).
// Output: z as fp16 in MFMA fragment layout.

__global__ void __launch_bounds__(256) k_agg(
    const __half* __restrict__ hs, const __half* __restrict__ h0u,
    __half* __restrict__ zf,
    const int* __restrict__ row_ptr, const int* __restrict__ deg,
    const int* __restrict__ col, const float* __restrict__ dinv) {
  int wid = (blockIdx.x * blockDim.x + threadIdx.x) >> 6;
  int lane = threadIdx.x & 63;
  if (wid >= NN) return;
  int g = lane >> 4;    // edge slot within chunk
  int fl = lane & 15;   // feature sub-lane: features [8*fl, 8*fl+8)
  int start = row_ptr[wid];
  int cnt = deg[wid] + 1;
  int nch = (cnt + 3) >> 2;

  float acc[8];
#pragma unroll
  for (int j = 0; j < 8; ++j) acc[j] = 0.f;

  auto load_chunk = [&](int ch, s16x8& v, float& m) {
    int e = ch * 4 + g;
    bool valid = e < cnt;
    int c = col[start + (valid ? e : 0)];
    m = valid ? 1.f : 0.f;
    v = *reinterpret_cast<const s16x8*>(&hs[(size_t)c * HIDC + fl * 8]);
  };

  s16x8 curv; float curm;
  load_chunk(0, curv, curm);
  for (int ch = 0; ch < nch; ++ch) {
    s16x8 nv = {}; float nm = 0.f;
    if (ch + 1 < nch) load_chunk(ch + 1, nv, nm);
    const __half2* hp = reinterpret_cast<const __half2*>(&curv);
#pragma unroll
    for (int j = 0; j < 4; ++j) {
      float2 f = __half22float2(hp[j]);
      acc[2 * j]     = fmaf(curm, f.x, acc[2 * j]);
      acc[2 * j + 1] = fmaf(curm, f.y, acc[2 * j + 1]);
    }
    curv = nv; curm = nm;
  }

  // combine the 4 group-partials: butterfly over lane bits 4..5
#pragma unroll
  for (int j = 0; j < 8; ++j) {
    acc[j] += __shfl_xor(acc[j], 16, 64);
    acc[j] += __shfl_xor(acc[j], 32, 64);
  }

  if (g == 0) {
    float dr = dinv[wid] * 0.9f;
    s16x8 r0 = *reinterpret_cast<const s16x8*>(&h0u[(size_t)wid * HIDC + fl * 8]);
    const __half2* r0p = reinterpret_cast<const __half2*>(&r0);
    f16x8 w;
#pragma unroll
    for (int j = 0; j < 4; ++j) {
      float2 f0 = __half22float2(r0p[j]);
      w[2 * j]     = (_Float16)fmaf(dr, acc[2 * j],     0.1f * f0.x);
      w[2 * j + 1] = (_Float16)fmaf(dr, acc[2 * j + 1], 0.1f * f0.y);
    }
    int base = (wid >> 4) * (HIDC * 16) + fl * 128 + (wid & 15) * 8;
    *reinterpret_cast<f16x8*>(&zf[base]) = w;
  }
}

// ---------------- fp16 fragment GEMM: C = epi(A @ B) ----------------
// K = 128, single mfma_f32_16x16x32_f16. One wave per 32-row chunk.
// Barrier-free: A frags from global (coalesced b128), B frags from global (L1-hot).
// EPI 0: relu -> fp16 scaled row-major (mid layer, feeds next agg)
// EPI 1: relu -> fp16 frag layout (last layer, feeds out GEMM)
// EPI 2: + bias -> fp32 row-major (output projection)

template <int NOUT, int EPI>
__global__ void __launch_bounds__(256) k_fgemm16(
    const __half* __restrict__ Af, const __half* __restrict__ Bf,
    const float* __restrict__ bias, const float* __restrict__ dinv,
    __half* __restrict__ Cs, __half* __restrict__ Cff, float* __restrict__ Cf) {
  constexpr int NF = NOUT / 16;
  int wv = threadIdx.x >> 6, lane = threadIdx.x & 63;
  int lr = lane & 15, kg = lane >> 4;
  int w32 = blockIdx.x * 4 + wv;
  if (w32 >= NW32) return;
  int row0 = w32 * 32;

  f32x4 acc[2][NF];
#pragma unroll
  for (int m = 0; m < 2; ++m)
#pragma unroll
    for (int n = 0; n < NF; ++n) acc[m][n] = {0.f, 0.f, 0.f, 0.f};

  const __half* Ab = Af + (size_t)(w32 * 2) * 2048 + kg * 128 + lr * 8;
  const __half* Bb = Bf + kg * 128 + lr * 8;

  f16x8 a0 = *reinterpret_cast<const f16x8*>(Ab);
  f16x8 a1 = *reinterpret_cast<const f16x8*>(Ab + 2048);
#pragma unroll
  for (int kt = 0; kt < 4; ++kt) {
    f16x8 n0, n1;
    if (kt < 3) {
      n0 = *reinterpret_cast<const f16x8*>(Ab + (kt + 1) * 512);
      n1 = *reinterpret_cast<const f16x8*>(Ab + 2048 + (kt + 1) * 512);
    }
#pragma unroll
    for (int n = 0; n < NF; ++n) {
      f16x8 b = *reinterpret_cast<const f16x8*>(Bb + n * 2048 + kt * 512);
      acc[0][n] = __builtin_amdgcn_mfma_f32_16x16x32_f16(a0, b, acc[0][n], 0, 0, 0);
      acc[1][n] = __builtin_amdgcn_mfma_f32_16x16x32_f16(a1, b, acc[1][n], 0, 0, 0);
    }
    if (kt < 3) { a0 = n0; a1 = n1; }
  }

  // epilogue: C(row = m*16 + kg*4 + q, col = n*16 + lr)
#pragma unroll
  for (int m = 0; m < 2; ++m) {
#pragma unroll
    for (int q = 0; q < 4; ++q) {
      int gr = row0 + m * 16 + kg * 4 + q;
      float dv = (EPI == 0) ? (dinv[gr] ) : 0.f;
#pragma unroll
      for (int n = 0; n < NF; ++n) {
        int gc = n * 16 + lr;
        float v = acc[m][n][q];
        if (EPI == 0) {
          v = fmaxf(v, 0.f);
          Cs[(size_t)gr * NOUT + gc] = __float2half(v * dv);
        } else if (EPI == 1) {
          v = fmaxf(v, 0.f);
          Cff[fraddr(gr, gc, HIDC)] = __float2half(v);
        } else {
          Cf[(size_t)gr * NOUT + gc] = v + bias[gc];
        }
      }
    }
  }
}

// ---------------- staged MFMA bf16x3 GEMM for the input projection ----------------
// h0 = relu(x @ W_in + b_in) -> fp16 unscaled + fp16 scaled.
// Register double-buffer: next K-tile's global loads issue during MFMA phase.

__global__ void __launch_bounds__(256) k_mgemm_in(
    const float* __restrict__ A, const unsigned short* __restrict__ Bhg,
    const unsigned short* __restrict__ Blg, const float* __restrict__ bias,
    __half* __restrict__ C16u, __half* __restrict__ C16s,
    const float* __restrict__ dinv, int M, int K, int Kp) {
  constexpr int BN = 128;
  constexpr int SK = 40;
  constexpr int NF = 4;
  __shared__ __align__(16) unsigned short Ah[128 * SK];
  __shared__ __align__(16) unsigned short Al[128 * SK];
  __shared__ __align__(16) unsigned short Bh[BN * SK];
  __shared__ __align__(16) unsigned short Bl[BN * SK];
  int tid = threadIdx.x;
  int wid = tid >> 6, lane = tid & 63;
  int wr = wid >> 1, wc = wid & 1;
  int lr = lane & 15, kg = lane >> 4;
  int row0 = blockIdx.x * 128;

  f32x4 acc[4][NF];
#pragma unroll
  for (int m = 0; m < 4; ++m)
#pragma unroll
    for (int n = 0; n < NF; ++n) acc[m][n] = {0.f, 0.f, 0.f, 0.f};

  float4 va[4];
  s16x8 vbh[2], vbl[2];
  auto issue_loads = [&](int kt) {
#pragma unroll
    for (int p = 0; p < 4; ++p) {
      int idx = tid + p * 256;
      int r = idx >> 3, kq = idx & 7;
      int gr = row0 + r, gk = kt + kq * 4;
      va[p] = make_float4(0.f, 0.f, 0.f, 0.f);
      if (gr < M && gk < K) va[p] = *reinterpret_cast<const float4*>(&A[(size_t)gr * K + gk]);
    }
#pragma unroll
    for (int p = 0; p < 2; ++p) {
      int idx = tid + p * 256;
      int n = idx >> 2, kq8 = idx & 3;
      size_t so = (size_t)n * Kp + kt + kq8 * 8;
      vbh[p] = *reinterpret_cast<const s16x8*>(&Bhg[so]);
      vbl[p] = *reinterpret_cast<const s16x8*>(&Blg[so]);
    }
  };

  issue_loads(0);
  for (int kt = 0; kt < Kp; kt += 32) {
    // convert + LDS write from regs
#pragma unroll
    for (int p = 0; p < 4; ++p) {
      int idx = tid + p * 256;
      int r = idx >> 3, kq = idx & 7;
      const float* vp = &va[p].x;
      s16x4 h4, l4;
#pragma unroll
      for (int e = 0; e < 4; ++e) {
        unsigned short h = f2bf_rn(vp[e]);
        h4[e] = (short)h;
        l4[e] = (short)f2bf_rn(vp[e] - bf2f(h));
      }
      *reinterpret_cast<s16x4*>(&Ah[r * SK + kq * 4]) = h4;
      *reinterpret_cast<s16x4*>(&Al[r * SK + kq * 4]) = l4;
    }
#pragma unroll
    for (int p = 0; p < 2; ++p) {
      int idx = tid + p * 256;
      int n = idx >> 2, kq8 = idx & 3;
      *reinterpret_cast<s16x8*>(&Bh[n * SK + kq8 * 8]) = vbh[p];
      *reinterpret_cast<s16x8*>(&Bl[n * SK + kq8 * 8]) = vbl[p];
    }
    __syncthreads();
    if (kt + 32 < Kp) issue_loads(kt + 32);  // overlaps with MFMA below

    bf16x8 afh[4], afl[4], bfh[NF], bfl[NF];
#pragma unroll
    for (int m = 0; m < 4; ++m) {
      int r = wr * 64 + m * 16 + lr;
      afh[m] = *reinterpret_cast<const bf16x8*>(&Ah[r * SK + kg * 8]);
      afl[m] = *reinterpret_cast<const bf16x8*>(&Al[r * SK + kg * 8]);
    }
#pragma unroll
    for (int n = 0; n < NF; ++n) {
      int c = wc * 64 + n * 16 + lr;
      bfh[n] = *reinterpret_cast<const bf16x8*>(&Bh[c * SK + kg * 8]);
      bfl[n] = *reinterpret_cast<const bf16x8*>(&Bl[c * SK + kg * 8]);
    }
#pragma unroll
    for (int m = 0; m < 4; ++m)
#pragma unroll
      for (int n = 0; n < NF; ++n) {
        acc[m][n] = __builtin_amdgcn_mfma_f32_16x16x32_bf16(afh[m], bfh[n], acc[m][n], 0, 0, 0);
        acc[m][n] = __builtin_amdgcn_mfma_f32_16x16x32_bf16(afl[m], bfh[n], acc[m][n], 0, 0, 0);
        acc[m][n] = __builtin_amdgcn_mfma_f32_16x16x32_bf16(afh[m], bfl[n], acc[m][n], 0, 0, 0);
      }
    __syncthreads();
  }

#pragma unroll
  for (int m = 0; m < 4; ++m) {
#pragma unroll
    for (int n = 0; n < NF; ++n) {
      int gc = wc * 64 + n * 16 + lr;
#pragma unroll
      for (int q = 0; q < 4; ++q) {
        int gr = row0 + wr * 64 + m * 16 + kg * 4 + q;
        if (gr < M) {
          float v = fmaxf(acc[m][n][q] + bias[gc], 0.f);
          C16u[(size_t)gr * BN + gc] = __float2half(v);
          C16s[(size_t)gr * BN + gc] = __float2half(v * dinv[gr]);
        }
      }
    }
  }
}

// ---------------- launch ----------------

extern "C" void kernel_launch(void* const* d_in, const int* in_sizes, int n_in,
                              void* d_out, int out_size, void* d_ws, size_t ws_size,
                              hipStream_t stream) {
  const float* x     = (const float*)d_in[0];
  const int*   ei    = (const int*)d_in[1];
  const float* W_in  = (const float*)d_in[2];
  const float* b_in  = (const float*)d_in[3];
  const float* W_cv  = (const float*)d_in[4];
  const float* W_out = (const float*)d_in[5];
  const float* b_out = (const float*)d_in[6];
  float* out = (float*)d_out;

  char* ws = (char*)d_ws;
  size_t off = 0;
  auto alloc = [&](size_t bytes) {
    char* p = ws + off;
    off = (off + bytes + 255) & ~(size_t)255;
    return p;
  };
  int*    deg     = (int*)alloc((size_t)NN * 4);
  int*    row_ptr = (int*)alloc((size_t)NN * 4);
  int*    cursor  = (int*)alloc((size_t)NN * 4);
  int*    bsum    = (int*)alloc(512 * 4);
  float*  dinv    = (float*)alloc((size_t)NN * 4);
  int*    col     = (int*)alloc((size_t)(EE + NN) * 4);
  __half* h016u   = (__half*)alloc((size_t)NN * HIDC * 2);
  __half* h016s   = (__half*)alloc((size_t)NN * HIDC * 2);
  __half* hsA     = (__half*)alloc((size_t)NN * HIDC * 2);
  __half* hsB     = (__half*)alloc((size_t)NN * HIDC * 2);
  __half* zf      = (__half*)alloc((size_t)NN * HIDC * 2);
  __half* hf      = (__half*)alloc((size_t)NN * HIDC * 2);
  __half* wcv16   = (__half*)alloc((size_t)NLAYER * HIDC * HIDC * 2);
  __half* wout16  = (__half*)alloc((size_t)OUTC * HIDC * 2);
  unsigned short* win_h = (unsigned short*)alloc((size_t)HIDC * 512 * 2);
  unsigned short* win_l = (unsigned short*)alloc((size_t)HIDC * 512 * 2);

  const int* srcp = ei;
  const int* dstp = ei + EE;

  hipMemsetAsync(deg, 0, (size_t)NN * 4, stream);
  k_count_deg<<<(EE + 255) / 256, 256, 0, stream>>>(dstp, deg, EE);
  int nb = (NN + 255) / 256;  // 391 <= 512
  k_scan_block_sums<<<nb, 256, 0, stream>>>(deg, bsum, NN);
  k_scan_partials<<<1, 512, 0, stream>>>(bsum, nb);
  k_scan_final<<<nb, 256, 0, stream>>>(deg, bsum, row_ptr, NN);
  k_init_rows<<<(NN + 255) / 256, 256, 0, stream>>>(deg, row_ptr, cursor, col, dinv, NN);
  k_fill_edges<<<(EE + 255) / 256, 256, 0, stream>>>(srcp, dstp, cursor, col, EE);

  // weight prep
  k_prep_w<<<(HIDC * 512 + 255) / 256, 256, 0, stream>>>(W_in, win_h, win_l, INC, HIDC, 512);
  for (int l = 0; l < NLAYER; ++l) {
    float beta = logf(0.5f / (float)(l + 1) + 1.0f);
    k_prep_wf16<<<(HIDC * HIDC + 255) / 256, 256, 0, stream>>>(
        W_cv + (size_t)l * HIDC * HIDC, wcv16 + (size_t)l * HIDC * HIDC,
        HIDC, HIDC, 1.0f - beta, beta);
  }
  k_prep_wf16<<<(OUTC * HIDC + 255) / 256, 256, 0, stream>>>(W_out, wout16, HIDC, OUTC,
                                                             0.f, 1.f);

  // h0 = relu(x @ W_in + b_in) -> fp16 unscaled + scaled
  k_mgemm_in<<<(NN + 127) / 128, 256, 0, stream>>>(x, win_h, win_l, b_in, h016u, h016s,
                                                   dinv, NN, INC, 512);

  int fgrid = (NW32 + 3) / 4;  // 782
  const __half* hcur = h016s;
  for (int l = 0; l < NLAYER; ++l) {
    k_agg<<<((size_t)NN * 64 + 255) / 256, 256, 0, stream>>>(hcur, h016u, zf,
                                                             row_ptr, deg, col, dinv);
    const __half* wl = wcv16 + (size_t)l * HIDC * HIDC;
    if (l < NLAYER - 1) {
      __half* tgt = (l & 1) ? hsB : hsA;
      k_fgemm16<128, 0><<<fgrid, 256, 0, stream>>>(zf, wl, nullptr, dinv,
                                                   tgt, nullptr, nullptr);
      hcur = tgt;
    } else {
      k_fgemm16<128, 1><<<fgrid, 256, 0, stream>>>(zf, wl, nullptr, nullptr,
                                                   nullptr, hf, nullptr);
    }
  }
  // out = h @ W_out + b_out
  k_fgemm16<64, 2><<<fgrid, 256, 0, stream>>>(hf, wout16, b_out, nullptr,
                                              nullptr, nullptr, out);
}

// Round 8
// 1092.759 us; speedup vs baseline: 2.5754x; 1.0517x over previous
//
#include <hip/hip_runtime.h>
#include <hip/hip_fp16.h>
#include <cmath>

#define NN 100000
#define EE 1600000
#define INC 500
#define HIDC 128
#define OUTC 64
#define NLAYER 8
#define NW32 3125           // NN / 32 exactly
#define GEMM_BLKS 782       // ceil(NN/128)
#define FILL_BLKS 6250      // ceil(EE/256)
#define FUSE_BLKS 7032      // 9*781 + 3 : bid%9==0 -> gemm (782), else fill (6250)

typedef float f32x4 __attribute__((ext_vector_type(4)));
typedef __bf16 bf16x8 __attribute__((ext_vector_type(8)));
typedef _Float16 f16x8 __attribute__((ext_vector_type(8)));
typedef short s16x4 __attribute__((ext_vector_type(4)));
typedef short s16x8 __attribute__((ext_vector_type(8)));

__device__ __forceinline__ unsigned short f2bf_rn(float f) {
  unsigned u = __float_as_uint(f);
  unsigned r = u + 0x7fffu + ((u >> 16) & 1u);
  return (unsigned short)(r >> 16);
}
__device__ __forceinline__ float bf2f(unsigned short h) {
  return __uint_as_float(((unsigned)h) << 16);
}

// frag layout addr for (row, k), K pitch Kp: [(row/16)][k/8][row%16][k%8]
__device__ __forceinline__ int fraddr(int row, int k, int Kp) {
  return (row >> 4) * (Kp * 16) + (k >> 3) * 128 + (row & 15) * 8 + (k & 7);
}

// ---------------- graph preprocessing ----------------

__global__ void k_count_deg(const int* __restrict__ dst, int* __restrict__ deg, int E) {
  int e = blockIdx.x * blockDim.x + threadIdx.x;
  if (e < E) atomicAdd(&deg[dst[e]], 1);
}

__global__ void k_scan_block_sums(const int* __restrict__ deg, int* __restrict__ bsum, int n) {
  __shared__ int sm[256];
  int i = blockIdx.x * 256 + threadIdx.x;
  int v = (i < n) ? deg[i] + 1 : 0;  // +1 for self-loop
  sm[threadIdx.x] = v;
  __syncthreads();
  for (int s = 128; s > 0; s >>= 1) {
    if (threadIdx.x < s) sm[threadIdx.x] += sm[threadIdx.x + s];
    __syncthreads();
  }
  if (threadIdx.x == 0) bsum[blockIdx.x] = sm[0];
}

__global__ void k_scan_partials(int* __restrict__ bsum, int nb) {
  __shared__ int sm[512];
  int t = threadIdx.x;
  sm[t] = (t < nb) ? bsum[t] : 0;
  __syncthreads();
  for (int s = 1; s < 512; s <<= 1) {
    int v = (t >= s) ? sm[t - s] : 0;
    __syncthreads();
    sm[t] += v;
    __syncthreads();
  }
  if (t < nb) bsum[t] = (t == 0) ? 0 : sm[t - 1];  // exclusive
}

__global__ void k_scan_final(const int* __restrict__ deg, const int* __restrict__ bsum,
                             int* __restrict__ row_ptr, int n) {
  __shared__ int sm[256];
  int i = blockIdx.x * 256 + threadIdx.x;
  int v = (i < n) ? deg[i] + 1 : 0;
  sm[threadIdx.x] = v;
  __syncthreads();
  for (int s = 1; s < 256; s <<= 1) {
    int u = (threadIdx.x >= s) ? sm[threadIdx.x - s] : 0;
    __syncthreads();
    sm[threadIdx.x] += u;
    __syncthreads();
  }
  if (i < n) row_ptr[i] = bsum[blockIdx.x] + sm[threadIdx.x] - v;  // exclusive
}

__global__ void k_init_rows(const int* __restrict__ deg, const int* __restrict__ row_ptr,
                            int* __restrict__ cursor, int* __restrict__ col,
                            float* __restrict__ dinv, int n) {
  int i = blockIdx.x * blockDim.x + threadIdx.x;
  if (i < n) {
    int rp = row_ptr[i];
    col[rp] = i;          // self-loop entry first (deterministic)
    cursor[i] = rp + 1;
    dinv[i] = rsqrtf((float)(deg[i] + 1));
  }
}

// ---- W_in -> FRAGMENT layout hi/lo bf16, Kp=512 ----

__global__ void k_prep_wfin(const float* __restrict__ W, unsigned short* __restrict__ fh,
                            unsigned short* __restrict__ fl) {
  int i = blockIdx.x * 256 + threadIdx.x;
  if (i >= HIDC * 512) return;
  int n = i / 512, k = i % 512;
  float v = (k < INC) ? W[(size_t)k * HIDC + n] : 0.f;
  unsigned short h = f2bf_rn(v);
  unsigned short l = f2bf_rn(v - bf2f(h));
  int a = fraddr(n, k, 512);
  fh[a] = h;
  fl[a] = l;
}

// ---- W -> fp16 fragment layout, optional identity fold: M = idc*I + ws*W ----

__global__ void k_prep_wf16(const float* __restrict__ W, __half* __restrict__ f,
                            int K, int N, float idc, float ws) {
  int i = blockIdx.x * 256 + threadIdx.x;
  if (i >= N * K) return;
  int n = i / K, k = i % K;
  float v = ws * W[(size_t)k * N + n] + ((k == n) ? idc : 0.f);
  f[fraddr(n, k, K)] = __float2half(v);
}

// ---------------- FUSED: CSR edge fill  ∥  input-projection GEMM ----------------
// bid%9==0 : one 128-row tile of h0 = relu(x @ W_in + b_in) (bf16x3 MFMA,
//            A staged via LDS w/ reg double-buffer, B frags direct from L2)
// else     : 256 edges of CSR fill (atomic cursor scatter)

__global__ void __launch_bounds__(256) k_fill_gemm(
    const int* __restrict__ src, const int* __restrict__ dst,
    int* __restrict__ cursor, int* __restrict__ col,
    const float* __restrict__ A, const unsigned short* __restrict__ Bfh,
    const unsigned short* __restrict__ Bfl, const float* __restrict__ bias,
    __half* __restrict__ C16u, __half* __restrict__ C16s,
    const float* __restrict__ dinv) {
  __shared__ __align__(16) unsigned short Ah[128 * 40];
  __shared__ __align__(16) unsigned short Al[128 * 40];
  int bid = blockIdx.x;
  int tid = threadIdx.x;

  if (bid % 9 != 0) {
    // ---------------- fill branch ----------------
    int fidx = bid - (bid / 9 + 1);
    int e = fidx * 256 + tid;
    if (e < EE) {
      int pos = atomicAdd(&cursor[dst[e]], 1);
      col[pos] = src[e];
    }
    return;
  }

  // ---------------- gemm branch ----------------
  int blk = bid / 9;
  int wid = tid >> 6, lane = tid & 63;
  int wr = wid >> 1, wc = wid & 1;
  int lr = lane & 15, kg = lane >> 4;
  int row0 = blk * 128;

  f32x4 acc[4][4];
#pragma unroll
  for (int m = 0; m < 4; ++m)
#pragma unroll
    for (int n = 0; n < 4; ++n) acc[m][n] = {0.f, 0.f, 0.f, 0.f};

  float4 va[4];
  auto issue_loads = [&](int kt) {
#pragma unroll
    for (int p = 0; p < 4; ++p) {
      int idx = tid + p * 256;
      int r = idx >> 3, kq = idx & 7;
      int gr = row0 + r, gk = kt + kq * 4;
      va[p] = make_float4(0.f, 0.f, 0.f, 0.f);
      if (gr < NN && gk < INC) va[p] = *reinterpret_cast<const float4*>(&A[(size_t)gr * INC + gk]);
    }
  };

  issue_loads(0);
  for (int kt = 0; kt < 512; kt += 32) {
    // convert regs -> LDS (hi/lo bf16)
#pragma unroll
    for (int p = 0; p < 4; ++p) {
      int idx = tid + p * 256;
      int r = idx >> 3, kq = idx & 7;
      const float* vp = &va[p].x;
      s16x4 h4, l4;
#pragma unroll
      for (int e = 0; e < 4; ++e) {
        unsigned short h = f2bf_rn(vp[e]);
        h4[e] = (short)h;
        l4[e] = (short)f2bf_rn(vp[e] - bf2f(h));
      }
      *reinterpret_cast<s16x4*>(&Ah[r * 40 + kq * 4]) = h4;
      *reinterpret_cast<s16x4*>(&Al[r * 40 + kq * 4]) = l4;
    }
    __syncthreads();
    if (kt + 32 < 512) issue_loads(kt + 32);  // overlaps MFMA below

    bf16x8 afh[4], afl[4];
#pragma unroll
    for (int m = 0; m < 4; ++m) {
      int r = wr * 64 + m * 16 + lr;
      afh[m] = *reinterpret_cast<const bf16x8*>(&Ah[r * 40 + kg * 8]);
      afl[m] = *reinterpret_cast<const bf16x8*>(&Al[r * 40 + kg * 8]);
    }
#pragma unroll
    for (int n = 0; n < 4; ++n) {
      size_t bb = (size_t)(wc * 4 + n) * 8192 + (size_t)(kt / 8 + kg) * 128 + lr * 8;
      bf16x8 bh = *reinterpret_cast<const bf16x8*>(&Bfh[bb]);
      bf16x8 bl = *reinterpret_cast<const bf16x8*>(&Bfl[bb]);
#pragma unroll
      for (int m = 0; m < 4; ++m) {
        acc[m][n] = __builtin_amdgcn_mfma_f32_16x16x32_bf16(afh[m], bh, acc[m][n], 0, 0, 0);
        acc[m][n] = __builtin_amdgcn_mfma_f32_16x16x32_bf16(afl[m], bh, acc[m][n], 0, 0, 0);
        acc[m][n] = __builtin_amdgcn_mfma_f32_16x16x32_bf16(afh[m], bl, acc[m][n], 0, 0, 0);
      }
    }
    __syncthreads();
  }

  // epilogue: C(row = m*16 + kg*4 + q, col = n*16 + lr)
#pragma unroll
  for (int m = 0; m < 4; ++m) {
#pragma unroll
    for (int n = 0; n < 4; ++n) {
      int gc = wc * 64 + n * 16 + lr;
#pragma unroll
      for (int q = 0; q < 4; ++q) {
        int gr = row0 + wr * 64 + m * 16 + kg * 4 + q;
        if (gr < NN) {
          float v = fmaxf(acc[m][n][q] + bias[gc], 0.f);
          C16u[(size_t)gr * HIDC + gc] = __float2half(v);
          C16s[(size_t)gr * HIDC + gc] = __float2half(v * dinv[gr]);
        }
      }
    }
  }
}

// ---------------- aggregation: z = 0.9*dinv_dst*sum(h'_src) + 0.1*h0 ----------------
// h' = dinv*h pre-scaled fp16. One wave per dst node. 4 lane-groups of 16;
// group g handles edge chunk slot g, lane loads 16B (8 fp16 features).
// Output: z as fp16 in MFMA fragment layout.

__global__ void __launch_bounds__(256) k_agg(
    const __half* __restrict__ hs, const __half* __restrict__ h0u,
    __half* __restrict__ zf,
    const int* __restrict__ row_ptr, const int* __restrict__ deg,
    const int* __restrict__ col, const float* __restrict__ dinv) {
  int wid = (blockIdx.x * blockDim.x + threadIdx.x) >> 6;
  int lane = threadIdx.x & 63;
  if (wid >= NN) return;
  int g = lane >> 4;    // edge slot within chunk
  int fl = lane & 15;   // feature sub-lane: features [8*fl, 8*fl+8)
  int start = row_ptr[wid];
  int cnt = deg[wid] + 1;
  int nch = (cnt + 3) >> 2;

  float acc[8];
#pragma unroll
  for (int j = 0; j < 8; ++j) acc[j] = 0.f;

  auto load_chunk = [&](int ch, s16x8& v, float& m) {
    int e = ch * 4 + g;
    bool valid = e < cnt;
    int c = col[start + (valid ? e : 0)];
    m = valid ? 1.f : 0.f;
    v = *reinterpret_cast<const s16x8*>(&hs[(size_t)c * HIDC + fl * 8]);
  };

  s16x8 curv; float curm;
  load_chunk(0, curv, curm);
  for (int ch = 0; ch < nch; ++ch) {
    s16x8 nv = {}; float nm = 0.f;
    if (ch + 1 < nch) load_chunk(ch + 1, nv, nm);
    const __half2* hp = reinterpret_cast<const __half2*>(&curv);
#pragma unroll
    for (int j = 0; j < 4; ++j) {
      float2 f = __half22float2(hp[j]);
      acc[2 * j]     = fmaf(curm, f.x, acc[2 * j]);
      acc[2 * j + 1] = fmaf(curm, f.y, acc[2 * j + 1]);
    }
    curv = nv; curm = nm;
  }

  // combine the 4 group-partials: butterfly over lane bits 4..5
#pragma unroll
  for (int j = 0; j < 8; ++j) {
    acc[j] += __shfl_xor(acc[j], 16, 64);
    acc[j] += __shfl_xor(acc[j], 32, 64);
  }

  if (g == 0) {
    float dr = dinv[wid] * 0.9f;
    s16x8 r0 = *reinterpret_cast<const s16x8*>(&h0u[(size_t)wid * HIDC + fl * 8]);
    const __half2* r0p = reinterpret_cast<const __half2*>(&r0);
    f16x8 w;
#pragma unroll
    for (int j = 0; j < 4; ++j) {
      float2 f0 = __half22float2(r0p[j]);
      w[2 * j]     = (_Float16)fmaf(dr, acc[2 * j],     0.1f * f0.x);
      w[2 * j + 1] = (_Float16)fmaf(dr, acc[2 * j + 1], 0.1f * f0.y);
    }
    int base = (wid >> 4) * (HIDC * 16) + fl * 128 + (wid & 15) * 8;
    *reinterpret_cast<f16x8*>(&zf[base]) = w;
  }
}

// ---------------- fp16 fragment GEMM: C = epi(A @ B) ----------------
// K = 128, single mfma_f32_16x16x32_f16. One wave per 32-row chunk.
// Barrier-free: A frags from global (coalesced b128), B frags from global (L1-hot).
// EPI 0: relu -> fp16 scaled row-major (mid layer, feeds next agg)
// EPI 1: relu -> fp16 frag layout (last layer, feeds out GEMM)
// EPI 2: + bias -> fp32 row-major (output projection)

template <int NOUT, int EPI>
__global__ void __launch_bounds__(256) k_fgemm16(
    const __half* __restrict__ Af, const __half* __restrict__ Bf,
    const float* __restrict__ bias, const float* __restrict__ dinv,
    __half* __restrict__ Cs, __half* __restrict__ Cff, float* __restrict__ Cf) {
  constexpr int NF = NOUT / 16;
  int wv = threadIdx.x >> 6, lane = threadIdx.x & 63;
  int lr = lane & 15, kg = lane >> 4;
  int w32 = blockIdx.x * 4 + wv;
  if (w32 >= NW32) return;
  int row0 = w32 * 32;

  f32x4 acc[2][NF];
#pragma unroll
  for (int m = 0; m < 2; ++m)
#pragma unroll
    for (int n = 0; n < NF; ++n) acc[m][n] = {0.f, 0.f, 0.f, 0.f};

  const __half* Ab = Af + (size_t)(w32 * 2) * 2048 + kg * 128 + lr * 8;
  const __half* Bb = Bf + kg * 128 + lr * 8;

  f16x8 a0 = *reinterpret_cast<const f16x8*>(Ab);
  f16x8 a1 = *reinterpret_cast<const f16x8*>(Ab + 2048);
#pragma unroll
  for (int kt = 0; kt < 4; ++kt) {
    f16x8 n0, n1;
    if (kt < 3) {
      n0 = *reinterpret_cast<const f16x8*>(Ab + (kt + 1) * 512);
      n1 = *reinterpret_cast<const f16x8*>(Ab + 2048 + (kt + 1) * 512);
    }
#pragma unroll
    for (int n = 0; n < NF; ++n) {
      f16x8 b = *reinterpret_cast<const f16x8*>(Bb + n * 2048 + kt * 512);
      acc[0][n] = __builtin_amdgcn_mfma_f32_16x16x32_f16(a0, b, acc[0][n], 0, 0, 0);
      acc[1][n] = __builtin_amdgcn_mfma_f32_16x16x32_f16(a1, b, acc[1][n], 0, 0, 0);
    }
    if (kt < 3) { a0 = n0; a1 = n1; }
  }

  // epilogue: C(row = m*16 + kg*4 + q, col = n*16 + lr)
#pragma unroll
  for (int m = 0; m < 2; ++m) {
#pragma unroll
    for (int q = 0; q < 4; ++q) {
      int gr = row0 + m * 16 + kg * 4 + q;
      float dv = (EPI == 0) ? (dinv[gr]) : 0.f;
#pragma unroll
      for (int n = 0; n < NF; ++n) {
        int gc = n * 16 + lr;
        float v = acc[m][n][q];
        if (EPI == 0) {
          v = fmaxf(v, 0.f);
          Cs[(size_t)gr * NOUT + gc] = __float2half(v * dv);
        } else if (EPI == 1) {
          v = fmaxf(v, 0.f);
          Cff[fraddr(gr, gc, HIDC)] = __float2half(v);
        } else {
          Cf[(size_t)gr * NOUT + gc] = v + bias[gc];
        }
      }
    }
  }
}

// ---------------- launch ----------------

extern "C" void kernel_launch(void* const* d_in, const int* in_sizes, int n_in,
                              void* d_out, int out_size, void* d_ws, size_t ws_size,
                              hipStream_t stream) {
  const float* x     = (const float*)d_in[0];
  const int*   ei    = (const int*)d_in[1];
  const float* W_in  = (const float*)d_in[2];
  const float* b_in  = (const float*)d_in[3];
  const float* W_cv  = (const float*)d_in[4];
  const float* W_out = (const float*)d_in[5];
  const float* b_out = (const float*)d_in[6];
  float* out = (float*)d_out;

  char* ws = (char*)d_ws;
  size_t off = 0;
  auto alloc = [&](size_t bytes) {
    char* p = ws + off;
    off = (off + bytes + 255) & ~(size_t)255;
    return p;
  };
  int*    deg     = (int*)alloc((size_t)NN * 4);
  int*    row_ptr = (int*)alloc((size_t)NN * 4);
  int*    cursor  = (int*)alloc((size_t)NN * 4);
  int*    bsum    = (int*)alloc(512 * 4);
  float*  dinv    = (float*)alloc((size_t)NN * 4);
  int*    col     = (int*)alloc((size_t)(EE + NN) * 4);
  __half* h016u   = (__half*)alloc((size_t)NN * HIDC * 2);
  __half* h016s   = (__half*)alloc((size_t)NN * HIDC * 2);
  __half* hsA     = (__half*)alloc((size_t)NN * HIDC * 2);
  __half* hsB     = (__half*)alloc((size_t)NN * HIDC * 2);
  __half* zf      = (__half*)alloc((size_t)NN * HIDC * 2);
  __half* hf      = (__half*)alloc((size_t)NN * HIDC * 2);
  __half* wcv16   = (__half*)alloc((size_t)NLAYER * HIDC * HIDC * 2);
  __half* wout16  = (__half*)alloc((size_t)OUTC * HIDC * 2);
  unsigned short* win_h = (unsigned short*)alloc((size_t)HIDC * 512 * 2);
  unsigned short* win_l = (unsigned short*)alloc((size_t)HIDC * 512 * 2);

  const int* srcp = ei;
  const int* dstp = ei + EE;

  hipMemsetAsync(deg, 0, (size_t)NN * 4, stream);
  k_count_deg<<<(EE + 255) / 256, 256, 0, stream>>>(dstp, deg, EE);
  int nb = (NN + 255) / 256;  // 391 <= 512
  k_scan_block_sums<<<nb, 256, 0, stream>>>(deg, bsum, NN);
  k_scan_partials<<<1, 512, 0, stream>>>(bsum, nb);
  k_scan_final<<<nb, 256, 0, stream>>>(deg, bsum, row_ptr, NN);
  k_init_rows<<<(NN + 255) / 256, 256, 0, stream>>>(deg, row_ptr, cursor, col, dinv, NN);

  // weight prep (before the fused kernel needs win_h/win_l)
  k_prep_wfin<<<(HIDC * 512 + 255) / 256, 256, 0, stream>>>(W_in, win_h, win_l);
  for (int l = 0; l < NLAYER; ++l) {
    float beta = logf(0.5f / (float)(l + 1) + 1.0f);
    k_prep_wf16<<<(HIDC * HIDC + 255) / 256, 256, 0, stream>>>(
        W_cv + (size_t)l * HIDC * HIDC, wcv16 + (size_t)l * HIDC * HIDC,
        HIDC, HIDC, 1.0f - beta, beta);
  }
  k_prep_wf16<<<(OUTC * HIDC + 255) / 256, 256, 0, stream>>>(W_out, wout16, HIDC, OUTC,
                                                             0.f, 1.f);

  // FUSED: CSR fill  ∥  h0 = relu(x @ W_in + b_in) -> fp16 unscaled + scaled
  k_fill_gemm<<<FUSE_BLKS, 256, 0, stream>>>(srcp, dstp, cursor, col,
                                             x, win_h, win_l, b_in,
                                             h016u, h016s, dinv);

  int fgrid = (NW32 + 3) / 4;  // 782
  const __half* hcur = h016s;
  for (int l = 0; l < NLAYER; ++l) {
    k_agg<<<((size_t)NN * 64 + 255) / 256, 256, 0, stream>>>(hcur, h016u, zf,
                                                             row_ptr, deg, col, dinv);
    const __half* wl = wcv16 + (size_t)l * HIDC * HIDC;
    if (l < NLAYER - 1) {
      __half* tgt = (l & 1) ? hsB : hsA;
      k_fgemm16<128, 0><<<fgrid, 256, 0, stream>>>(zf, wl, nullptr, dinv,
                                                   tgt, nullptr, nullptr);
      hcur = tgt;
    } else {
      k_fgemm16<128, 1><<<fgrid, 256, 0, stream>>>(zf, wl, nullptr, nullptr,
                                                   nullptr, hf, nullptr);
    }
  }
  // out = h @ W_out + b_out
  k_fgemm16<64, 2><<<fgrid, 256, 0, stream>>>(hf, wout16, b_out, nullptr,
                                              nullptr, nullptr, out);
}